// Round 7
// baseline (604.035 us; speedup 1.0000x reference)
//
#include <hip/hip_runtime.h>
#include <hip/hip_bf16.h>
#include <math.h>

// Problem constants
constexpr int N = 10000;
constexpr int E = 160000;
constexpr int B = 16;
constexpr int PC = 625;     // pool partial chunks (= prepool grid)
constexpr int NBIN = 1250;  // edge dst buckets (dst>>3)

typedef short bf16x8 __attribute__((ext_vector_type(8)));
typedef float f32x4 __attribute__((ext_vector_type(4)));

__device__ __forceinline__ float silu_f(float x) {
    return x / (1.0f + __expf(-x));
}

// ---------------- K1: embedding h = TP(concat(x,anf), na, W_emb) + b ----------------
__global__ __launch_bounds__(256) void k_embed(
        const float* __restrict__ x, const float* __restrict__ anf,
        const float* __restrict__ na, const float* __restrict__ W,
        const float* __restrict__ b, float* __restrict__ h) {
    int wv = threadIdx.x >> 6;
    int k = threadIdx.x & 63;
    int n = blockIdx.x * 4 + wv;
    float naR[8];
#pragma unroll
    for (int j = 0; j < 8; ++j) naR[j] = na[n * 8 + j];
    float acc = b[k];
#pragma unroll
    for (int i = 0; i < 17; ++i) {
        float xi = (i < 16) ? x[n * 16 + i] : anf[n];
#pragma unroll
        for (int j = 0; j < 8; ++j)
            acc = fmaf(xi * naR[j], W[(i * 8 + j) * 64 + k], acc);
    }
    h[(size_t)n * 64 + k] = acc;
}

// ---------------- fused weight reorder (all 6 reorders in one launch) ----------------
__device__ __forceinline__ void hilo_store(float wv, __hip_bfloat16* hi, __hip_bfloat16* lo, int idx) {
    __hip_bfloat16 hh = __float2bfloat16(wv);
    hi[idx] = hh;
    lo[idx] = __float2bfloat16(wv - __bfloat162float(hh));
}
__device__ __forceinline__ float zr64_val(const float* Wsrc, int idx) {
    int l = idx >> 15;
    int rem = idx & 32767;
    int kk = rem >> 11, nt = (rem >> 9) & 3, c = (rem >> 5) & 15, q = (rem >> 3) & 3, j = rem & 7;
    return Wsrc[(size_t)l * 32768 + (size_t)(kk * 4 + q) * 512 + j * 64 + nt * 16 + c];
}
__device__ __forceinline__ float wu1_val(const float* Wu1, int idx) {
    int l = idx / 67584;
    int rem = idx % 67584;
    int kk = rem / 2048;
    int r2 = rem % 2048;
    int nt = (r2 >> 9) & 3, c = (r2 >> 5) & 15, q = (r2 >> 3) & 3, j = r2 & 7;
    int i = kk * 4 + q;
    return (i < 129) ? Wu1[(size_t)l * 129 * 512 + (size_t)i * 512 + j * 64 + nt * 16 + c] : 0.f;
}
__device__ __forceinline__ float wm1p_val(const float* Wm1, int idx) {
    int l = idx / 98304;
    int rem = idx % 98304;
    int kk = rem / 32768;
    int r2 = rem % 32768;
    int nt = (r2 >> 9) & 63, c = (r2 >> 5) & 15, q = (r2 >> 3) & 3, t = r2 & 7;
    int i = kk * 32 + q * 8 + t;
    int col = nt * 16 + c;
    int part = col >> 9, kd = (col >> 3) & 63, j = col & 7;
    if (i >= 65) return 0.f;
    return Wm1[(size_t)l * 131 * 512 + (size_t)(part ? 65 + i : i) * 512 + j * 64 + kd];
}
__global__ __launch_bounds__(256) void k_reorder(
        const float* __restrict__ Wm2, const float* __restrict__ Wu2,
        const float* __restrict__ Wp1, const float* __restrict__ Wp2,
        const float* __restrict__ Wu1, const float* __restrict__ Wm1,
        __hip_bfloat16* W2hi, __hip_bfloat16* W2lo,
        __hip_bfloat16* Wu2hi, __hip_bfloat16* Wu2lo,
        __hip_bfloat16* Wp1hi, __hip_bfloat16* Wp1lo,
        __hip_bfloat16* Wp2hi, __hip_bfloat16* Wp2lo,
        __hip_bfloat16* Wu1hi, __hip_bfloat16* Wu1lo,
        __hip_bfloat16* Wm1phi, __hip_bfloat16* Wm1plo) {
    int idx = blockIdx.x * 256 + threadIdx.x;
    if (idx < 65536)        hilo_store(zr64_val(Wm2, idx), W2hi, W2lo, idx);
    else if (idx < 131072) { int i2 = idx - 65536;  hilo_store(zr64_val(Wu2, i2), Wu2hi, Wu2lo, i2); }
    else if (idx < 163840) { int i2 = idx - 131072; hilo_store(zr64_val(Wp1, i2), Wp1hi, Wp1lo, i2); }
    else if (idx < 196608) { int i2 = idx - 163840; hilo_store(zr64_val(Wp2, i2), Wp2hi, Wp2lo, i2); }
    else if (idx < 331776) { int i2 = idx - 196608; hilo_store(wu1_val(Wu1, i2), Wu1hi, Wu1lo, i2); }
    else if (idx < 528384) { int i2 = idx - 331776; hilo_store(wm1p_val(Wm1, i2), Wm1phi, Wm1plo, i2); }
}

// ---------------- edge bucketing: counting sort by dst>>3 ----------------
__global__ __launch_bounds__(256) void k_hist(const int* __restrict__ eidx, int* __restrict__ hist) {
    int e = blockIdx.x * 256 + threadIdx.x;
    if (e < E) atomicAdd(&hist[eidx[E + e] >> 3], 1);
}
__global__ __launch_bounds__(256) void k_scan(const int* __restrict__ hist, int* __restrict__ offs) {
    __shared__ int sums[257];
    int tid = threadIdx.x;
    int base = tid * 5;
    int loc[5];
    int s = 0;
#pragma unroll
    for (int i = 0; i < 5; ++i) {
        int bb = base + i;
        int v = (bb < NBIN) ? hist[bb] : 0;
        loc[i] = s; s += v;
    }
    sums[tid + 1] = s;
    if (tid == 0) sums[0] = 0;
    __syncthreads();
    if (tid == 0)
        for (int i = 1; i <= 256; ++i) sums[i] += sums[i - 1];
    __syncthreads();
    int b0 = sums[tid];
#pragma unroll
    for (int i = 0; i < 5; ++i) {
        int bb = base + i;
        if (bb < NBIN) offs[bb] = b0 + loc[i];
    }
}
__global__ __launch_bounds__(256) void k_scatter(const int* __restrict__ eidx,
                                                 int* __restrict__ offs, int* __restrict__ perm) {
    int e = blockIdx.x * 256 + threadIdx.x;
    if (e < E) {
        int bin = eidx[E + e] >> 3;
        int pos = atomicAdd(&offs[bin], 1);
        perm[pos] = e;
    }
}

// ---------------- K2: precompute P = ha @ B (MFMA, 16 nodes, 4 waves split Nout) + zero agg ----------------
__global__ __launch_bounds__(256) void k_pre_mfma(
        const float* __restrict__ h, const float* __restrict__ anf,
        const __hip_bfloat16* __restrict__ Bhi, const __hip_bfloat16* __restrict__ Blo,
        __hip_bfloat16* __restrict__ P, float* __restrict__ agg) {
    __shared__ __align__(16) __hip_bfloat16 ha_s[16 * 96];
    int tid = threadIdx.x;
    int w = tid >> 6, l = tid & 63;
    int n0 = blockIdx.x * 16;
    // zero this block's slice of agg (625*1024 == N*64)
    float4 z4 = {0.f, 0.f, 0.f, 0.f};
    ((float4*)(agg + (size_t)blockIdx.x * 1024))[tid] = z4;
    for (int idx = tid; idx < 16 * 96; idx += 256) {
        int r = idx / 96, c = idx % 96;
        float v = (c < 64) ? h[(size_t)(n0 + r) * 64 + c] : (c == 64 ? anf[n0 + r] : 0.f);
        ha_s[idx] = __float2bfloat16(v);
    }
    __syncthreads();
    int c16 = l & 15, q = l >> 4;
    bf16x8 aF[3];
#pragma unroll
    for (int kk = 0; kk < 3; ++kk)
        aF[kk] = *(const bf16x8*)&ha_s[c16 * 96 + kk * 32 + q * 8];
    int lofs = (c16 * 4 + q) * 8;
    f32x4 zero4 = {0.f, 0.f, 0.f, 0.f};
#pragma unroll
    for (int ntg = 0; ntg < 2; ++ntg) {
        f32x4 acc[8];
#pragma unroll
        for (int t = 0; t < 8; ++t) acc[t] = zero4;
#pragma unroll
        for (int kk = 0; kk < 3; ++kk) {
#pragma unroll
            for (int nt2 = 0; nt2 < 8; ++nt2) {
                int nt = w * 16 + ntg * 8 + nt2;
                bf16x8 bh = *(const bf16x8*)(Bhi + (size_t)(kk * 64 + nt) * 512 + lofs);
                bf16x8 bl = *(const bf16x8*)(Blo + (size_t)(kk * 64 + nt) * 512 + lofs);
                acc[nt2] = __builtin_amdgcn_mfma_f32_16x16x32_bf16(aF[kk], bh, acc[nt2], 0, 0, 0);
                acc[nt2] = __builtin_amdgcn_mfma_f32_16x16x32_bf16(aF[kk], bl, acc[nt2], 0, 0, 0);
            }
        }
#pragma unroll
        for (int nt2 = 0; nt2 < 8; ++nt2)
#pragma unroll
            for (int r = 0; r < 4; ++r) {
                int n = n0 + q * 4 + r;
                P[(size_t)n * 1024 + (w * 16 + ntg * 8 + nt2) * 16 + c16] = __float2bfloat16(acc[nt2][r]);
            }
    }
}

// ---------------- K3: edge kernel (R5-proven shape, dst-bucketed edge order via perm) ----------------
constexpr int MS = 72;
__global__ __launch_bounds__(256, 3) void k_edge(
        const int* __restrict__ perm,
        const int* __restrict__ eidx, const float* __restrict__ ea,
        const float* __restrict__ amf, const __hip_bfloat16* __restrict__ P,
        const float* __restrict__ Wm1_l, const float* __restrict__ bm1_l,
        const __hip_bfloat16* __restrict__ W2hi, const __hip_bfloat16* __restrict__ W2lo,
        const float* __restrict__ bm2_l, float* __restrict__ agg) {
    __shared__ __align__(16) __hip_bfloat16 m_s[128 * MS];
    __shared__ float ea_s[128][9];
    __shared__ float amf_s[128];
    __shared__ int src_s[128], dst_s[128], ep_s[128];
    __shared__ float bm1_s[64], bm2_s[64];
    int tid = threadIdx.x;
    int l = tid & 63, w = tid >> 6;
    int e0 = blockIdx.x * 128;
    for (int idx = tid; idx < 128; idx += 256) {
        int e = perm[e0 + idx];
        ep_s[idx] = e;
        src_s[idx] = eidx[e];
        dst_s[idx] = eidx[E + e];
        amf_s[idx] = amf[e];
    }
    if (tid < 64) { bm1_s[tid] = bm1_l[tid]; bm2_s[tid] = bm2_l[tid]; }
    float w130R[8];
#pragma unroll
    for (int j = 0; j < 8; ++j) w130R[j] = Wm1_l[130 * 512 + j * 64 + l];
    __syncthreads();
    for (int idx = tid; idx < 1024; idx += 256)
        ea_s[idx >> 3][idx & 7] = ea[(size_t)ep_s[idx >> 3] * 8 + (idx & 7)];
    __syncthreads();

    // ---- phase 1: m = bf16(silu(m1)), 2 vector loads per edge ----
    float bm1k = bm1_s[l];
#pragma unroll 4
    for (int q = 0; q < 32; ++q) {
        int le = w * 32 + q;
        bf16x8 p1 = *(const bf16x8*)(P + (size_t)dst_s[le] * 1024 + l * 8);
        bf16x8 p2 = *(const bf16x8*)(P + (size_t)src_s[le] * 1024 + 512 + l * 8);
        float amfe = amf_s[le];
        float macc = bm1k;
#pragma unroll
        for (int j = 0; j < 8; ++j) {
            union { short s; __hip_bfloat16 b; } u1c, u2c;
            u1c.s = p1[j]; u2c.s = p2[j];
            float s = __bfloat162float(u1c.b) + __bfloat162float(u2c.b) + amfe * w130R[j];
            macc = fmaf(ea_s[le][j], s, macc);
        }
        m_s[le * MS + l] = __float2bfloat16(silu_f(macc));
    }
    __syncthreads();

    // ---- phase 2: z-GEMM  D[e][kd] = sum_ij (m[e][i]*ea[e][j]) * W2flat[ij][kd] ----
    int c16 = l & 15, q = l >> 4;
    int e0w = w * 32;
    float eaA[2][8];
#pragma unroll
    for (int mt = 0; mt < 2; ++mt)
#pragma unroll
        for (int j = 0; j < 8; ++j) eaA[mt][j] = ea_s[e0w + mt * 16 + c16][j];

    f32x4 acc[2][4];
    f32x4 zero4 = {0.f, 0.f, 0.f, 0.f};
#pragma unroll
    for (int mt = 0; mt < 2; ++mt)
#pragma unroll
        for (int nt = 0; nt < 4; ++nt) acc[mt][nt] = zero4;

    int lofs = (c16 * 4 + q) * 8;
#pragma unroll 2
    for (int kk = 0; kk < 16; ++kk) {
        bf16x8 bh[4], bl[4];
#pragma unroll
        for (int nt = 0; nt < 4; ++nt) {
            int off = (kk * 4 + nt) * 512 + lofs;
            bh[nt] = *(const bf16x8*)(W2hi + off);
            bl[nt] = *(const bf16x8*)(W2lo + off);
        }
#pragma unroll
        for (int mt = 0; mt < 2; ++mt) {
            float mv = __bfloat162float(m_s[(e0w + mt * 16 + c16) * MS + kk * 4 + q]);
            union { bf16x8 v; __hip_bfloat16 h[8]; } au;
#pragma unroll
            for (int j = 0; j < 8; ++j) au.h[j] = __float2bfloat16(mv * eaA[mt][j]);
#pragma unroll
            for (int nt = 0; nt < 4; ++nt) {
                acc[mt][nt] = __builtin_amdgcn_mfma_f32_16x16x32_bf16(au.v, bh[nt], acc[mt][nt], 0, 0, 0);
                acc[mt][nt] = __builtin_amdgcn_mfma_f32_16x16x32_bf16(au.v, bl[nt], acc[mt][nt], 0, 0, 0);
            }
        }
    }
#pragma unroll
    for (int mt = 0; mt < 2; ++mt)
#pragma unroll
        for (int nt = 0; nt < 4; ++nt) {
            int kd = nt * 16 + c16;
            float bias = bm2_s[kd];
#pragma unroll
            for (int r = 0; r < 4; ++r) {
                int e = e0w + mt * 16 + q * 4 + r;
                float v = silu_f(bias + acc[mt][nt][r]);
                atomicAdd(&agg[(size_t)dst_s[e] * 64 + kd], v);
            }
        }
}

// ---------------- K4: node update, fused z-GEMMs, 4 waves split K + LDS reduce ----------------
__global__ __launch_bounds__(256) void k_upd_mfma(
        const float* __restrict__ h_in, const float* __restrict__ anf,
        const float* __restrict__ na, const float* __restrict__ agg,
        const __hip_bfloat16* __restrict__ W1hi, const __hip_bfloat16* __restrict__ W1lo,
        const float* __restrict__ bu1_l,
        const __hip_bfloat16* __restrict__ W2hi_, const __hip_bfloat16* __restrict__ W2lo_,
        const float* __restrict__ bu2_l,
        float* __restrict__ h) {
    __shared__ __align__(16) __hip_bfloat16 xa_s[16 * 136];
    __shared__ __align__(16) __hip_bfloat16 u1_s[16 * 72];
    __shared__ float part_s[4][16][64];
    int tid = threadIdx.x;
    int w = tid >> 6, l = tid & 63;
    int n0 = blockIdx.x * 16;
    for (int idx = tid; idx < 16 * 132; idx += 256) {
        int r = idx / 132, c = idx % 132;
        int n = n0 + r;
        float v;
        if (c < 64) v = h_in[(size_t)n * 64 + c];
        else if (c == 64) v = anf[n];
        else if (c < 129) v = agg[(size_t)n * 64 + (c - 65)];
        else v = 0.f;
        xa_s[r * 136 + c] = __float2bfloat16(v);
    }
    int c16 = l & 15, q = l >> 4;
    float naA[8];
#pragma unroll
    for (int j = 0; j < 8; ++j) naA[j] = na[(size_t)(n0 + c16) * 8 + j];
    __syncthreads();
    int lofs = (c16 * 4 + q) * 8;
    f32x4 zero4 = {0.f, 0.f, 0.f, 0.f};
    f32x4 acc[4];
#pragma unroll
    for (int nt = 0; nt < 4; ++nt) acc[nt] = zero4;
    for (int kk = w; kk < 33; kk += 4) {
        bf16x8 bh[4], bl[4];
#pragma unroll
        for (int nt = 0; nt < 4; ++nt) {
            int off = (kk * 4 + nt) * 512 + lofs;
            bh[nt] = *(const bf16x8*)(W1hi + off);
            bl[nt] = *(const bf16x8*)(W1lo + off);
        }
        float mv = __bfloat162float(xa_s[c16 * 136 + kk * 4 + q]);
        union { bf16x8 v; __hip_bfloat16 hx[8]; } au;
#pragma unroll
        for (int j = 0; j < 8; ++j) au.hx[j] = __float2bfloat16(mv * naA[j]);
#pragma unroll
        for (int nt = 0; nt < 4; ++nt) {
            acc[nt] = __builtin_amdgcn_mfma_f32_16x16x32_bf16(au.v, bh[nt], acc[nt], 0, 0, 0);
            acc[nt] = __builtin_amdgcn_mfma_f32_16x16x32_bf16(au.v, bl[nt], acc[nt], 0, 0, 0);
        }
    }
#pragma unroll
    for (int nt = 0; nt < 4; ++nt)
#pragma unroll
        for (int r = 0; r < 4; ++r) part_s[w][q * 4 + r][nt * 16 + c16] = acc[nt][r];
    __syncthreads();
    for (int t = tid; t < 1024; t += 256) {
        int row = t >> 6, col = t & 63;
        float v = part_s[0][row][col] + part_s[1][row][col] + part_s[2][row][col] +
                  part_s[3][row][col] + bu1_l[col];
        u1_s[row * 72 + col] = __float2bfloat16(silu_f(v));
    }
    __syncthreads();
    f32x4 acc2[4];
#pragma unroll
    for (int nt = 0; nt < 4; ++nt) acc2[nt] = zero4;
    for (int kk = w; kk < 16; kk += 4) {
        bf16x8 bh[4], bl[4];
#pragma unroll
        for (int nt = 0; nt < 4; ++nt) {
            int off = (kk * 4 + nt) * 512 + lofs;
            bh[nt] = *(const bf16x8*)(W2hi_ + off);
            bl[nt] = *(const bf16x8*)(W2lo_ + off);
        }
        float mv = __bfloat162float(u1_s[c16 * 72 + kk * 4 + q]);
        union { bf16x8 v; __hip_bfloat16 hx[8]; } au;
#pragma unroll
        for (int j = 0; j < 8; ++j) au.hx[j] = __float2bfloat16(mv * naA[j]);
#pragma unroll
        for (int nt = 0; nt < 4; ++nt) {
            acc2[nt] = __builtin_amdgcn_mfma_f32_16x16x32_bf16(au.v, bh[nt], acc2[nt], 0, 0, 0);
            acc2[nt] = __builtin_amdgcn_mfma_f32_16x16x32_bf16(au.v, bl[nt], acc2[nt], 0, 0, 0);
        }
    }
    __syncthreads();
#pragma unroll
    for (int nt = 0; nt < 4; ++nt)
#pragma unroll
        for (int r = 0; r < 4; ++r) part_s[w][q * 4 + r][nt * 16 + c16] = acc2[nt][r];
    __syncthreads();
    for (int t = tid; t < 1024; t += 256) {
        int row = t >> 6, col = t & 63;
        float v = part_s[0][row][col] + part_s[1][row][col] + part_s[2][row][col] +
                  part_s[3][row][col] + bu2_l[col];
        h[(size_t)(n0 + row) * 64 + col] += v;
    }
}

// ---------------- K6: prepool, fused z-GEMMs + in-block pooling (4-wave K-split) ----------------
__global__ __launch_bounds__(256) void k_prepool_mfma(
        const float* __restrict__ h, const float* __restrict__ na,
        const int* __restrict__ batch,
        const __hip_bfloat16* __restrict__ W1hi, const __hip_bfloat16* __restrict__ W1lo,
        const float* __restrict__ bp1,
        const __hip_bfloat16* __restrict__ W2hi_, const __hip_bfloat16* __restrict__ W2lo_,
        const float* __restrict__ bp2,
        float* __restrict__ partial_p, float* __restrict__ partial_cnt) {
    __shared__ __align__(16) __hip_bfloat16 xa_s[16 * 72];
    __shared__ __align__(16) __hip_bfloat16 u1_s[16 * 72];
    __shared__ float part_s[4][16][64];
    __shared__ float pool_s[16][64];
    __shared__ float cnt_s[16];
    __shared__ int batch_s[16];
    int tid = threadIdx.x;
    int w = tid >> 6, l = tid & 63;
    int n0 = blockIdx.x * 16;
    for (int idx = tid; idx < 1024; idx += 256) pool_s[idx >> 6][idx & 63] = 0.f;
    if (tid < 16) { cnt_s[tid] = 0.f; batch_s[tid] = batch[n0 + tid]; }
    for (int idx = tid; idx < 16 * 64; idx += 256) {
        int r = idx >> 6, c = idx & 63;
        xa_s[r * 72 + c] = __float2bfloat16(h[(size_t)(n0 + r) * 64 + c]);
    }
    int c16 = l & 15, q = l >> 4;
    float naA[8];
#pragma unroll
    for (int j = 0; j < 8; ++j) naA[j] = na[(size_t)(n0 + c16) * 8 + j];
    __syncthreads();
    if (tid < 16) atomicAdd(&cnt_s[batch_s[tid]], 1.0f);
    int lofs = (c16 * 4 + q) * 8;
    f32x4 zero4 = {0.f, 0.f, 0.f, 0.f};
    f32x4 acc[4];
#pragma unroll
    for (int nt = 0; nt < 4; ++nt) acc[nt] = zero4;
    for (int kk = w; kk < 16; kk += 4) {
        bf16x8 bh[4], bl[4];
#pragma unroll
        for (int nt = 0; nt < 4; ++nt) {
            int off = (kk * 4 + nt) * 512 + lofs;
            bh[nt] = *(const bf16x8*)(W1hi + off);
            bl[nt] = *(const bf16x8*)(W1lo + off);
        }
        float mv = __bfloat162float(xa_s[c16 * 72 + kk * 4 + q]);
        union { bf16x8 v; __hip_bfloat16 hx[8]; } au;
#pragma unroll
        for (int j = 0; j < 8; ++j) au.hx[j] = __float2bfloat16(mv * naA[j]);
#pragma unroll
        for (int nt = 0; nt < 4; ++nt) {
            acc[nt] = __builtin_amdgcn_mfma_f32_16x16x32_bf16(au.v, bh[nt], acc[nt], 0, 0, 0);
            acc[nt] = __builtin_amdgcn_mfma_f32_16x16x32_bf16(au.v, bl[nt], acc[nt], 0, 0, 0);
        }
    }
#pragma unroll
    for (int nt = 0; nt < 4; ++nt)
#pragma unroll
        for (int r = 0; r < 4; ++r) part_s[w][q * 4 + r][nt * 16 + c16] = acc[nt][r];
    __syncthreads();
    for (int t = tid; t < 1024; t += 256) {
        int row = t >> 6, col = t & 63;
        float v = part_s[0][row][col] + part_s[1][row][col] + part_s[2][row][col] +
                  part_s[3][row][col] + bp1[col];
        u1_s[row * 72 + col] = __float2bfloat16(silu_f(v));
    }
    __syncthreads();
    f32x4 acc2[4];
#pragma unroll
    for (int nt = 0; nt < 4; ++nt) acc2[nt] = zero4;
    for (int kk = w; kk < 16; kk += 4) {
        bf16x8 bh[4], bl[4];
#pragma unroll
        for (int nt = 0; nt < 4; ++nt) {
            int off = (kk * 4 + nt) * 512 + lofs;
            bh[nt] = *(const bf16x8*)(W2hi_ + off);
            bl[nt] = *(const bf16x8*)(W2lo_ + off);
        }
        float mv = __bfloat162float(u1_s[c16 * 72 + kk * 4 + q]);
        union { bf16x8 v; __hip_bfloat16 hx[8]; } au;
#pragma unroll
        for (int j = 0; j < 8; ++j) au.hx[j] = __float2bfloat16(mv * naA[j]);
#pragma unroll
        for (int nt = 0; nt < 4; ++nt) {
            acc2[nt] = __builtin_amdgcn_mfma_f32_16x16x32_bf16(au.v, bh[nt], acc2[nt], 0, 0, 0);
            acc2[nt] = __builtin_amdgcn_mfma_f32_16x16x32_bf16(au.v, bl[nt], acc2[nt], 0, 0, 0);
        }
    }
    __syncthreads();
#pragma unroll
    for (int nt = 0; nt < 4; ++nt)
#pragma unroll
        for (int r = 0; r < 4; ++r) part_s[w][q * 4 + r][nt * 16 + c16] = acc2[nt][r];
    __syncthreads();
    for (int t = tid; t < 1024; t += 256) {
        int row = t >> 6, col = t & 63;
        float v = part_s[0][row][col] + part_s[1][row][col] + part_s[2][row][col] +
                  part_s[3][row][col] + bp2[col];
        atomicAdd(&pool_s[batch_s[row]][col], v);
    }
    __syncthreads();
    for (int t = tid; t < 1024; t += 256)
        partial_p[(size_t)blockIdx.x * 1024 + t] = pool_s[t >> 6][t & 63];
    if (tid < 16) partial_cnt[blockIdx.x * 16 + tid] = cnt_s[tid];
}

// ---------------- K7: reduce 625 partials, mean, final MLP (one block per graph) ----------------
__global__ __launch_bounds__(256) void k_final(
        const float* __restrict__ partial_p, const float* __restrict__ partial_cnt,
        const float* __restrict__ Wq1, const float* __restrict__ bq1,
        const float* __restrict__ Wq2, const float* __restrict__ bq2,
        float* __restrict__ out) {
    __shared__ float red[4][64];
    __shared__ float cred[4];
    __shared__ float g_s[64];
    int b = blockIdx.x;
    int tid = threadIdx.x;
    int k = tid & 63, part = tid >> 6;
    float s = 0.f;
    for (int c = part; c < PC; c += 4) s += partial_p[(size_t)c * 1024 + b * 64 + k];
    red[part][k] = s;
    if (k == 0) {
        float cc = 0.f;
        for (int c = part; c < PC; c += 4) cc += partial_cnt[c * 16 + b];
        cred[part] = cc;
    }
    __syncthreads();
    if (tid < 64) {
        float cnt = cred[0] + cred[1] + cred[2] + cred[3];
        g_s[k] = (red[0][k] + red[1][k] + red[2][k] + red[3][k]) / fmaxf(cnt, 1.0f);
    }
    __syncthreads();
    if (tid < 64) {
        float acc = bq1[k];
#pragma unroll
        for (int i = 0; i < 64; ++i) acc = fmaf(g_s[i], Wq1[i * 64 + k], acc);
        float v = silu_f(acc) * Wq2[k];
#pragma unroll
        for (int off = 32; off > 0; off >>= 1) v += __shfl_down(v, off, 64);
        if (k == 0) out[b] = v + bq2[0];
    }
}

extern "C" void kernel_launch(void* const* d_in, const int* in_sizes, int n_in,
                              void* d_out, int out_size, void* d_ws, size_t ws_size,
                              hipStream_t stream) {
    const float* x    = (const float*)d_in[0];
    const int*   eidx = (const int*)  d_in[1];
    const float* ea   = (const float*)d_in[2];
    const float* na   = (const float*)d_in[3];
    const float* amf  = (const float*)d_in[4];
    const float* anf  = (const float*)d_in[5];
    const int*   batch= (const int*)  d_in[6];
    const float* W_emb= (const float*)d_in[7];
    const float* b_emb= (const float*)d_in[8];
    const float* Wm1  = (const float*)d_in[9];
    const float* bm1  = (const float*)d_in[10];
    const float* Wm2  = (const float*)d_in[11];
    const float* bm2  = (const float*)d_in[12];
    const float* Wu1  = (const float*)d_in[13];
    const float* bu1  = (const float*)d_in[14];
    const float* Wu2  = (const float*)d_in[15];
    const float* bu2  = (const float*)d_in[16];
    const float* Wp1  = (const float*)d_in[17];
    const float* bp1  = (const float*)d_in[18];
    const float* Wp2  = (const float*)d_in[19];
    const float* bp2  = (const float*)d_in[20];
    const float* Wq1  = (const float*)d_in[21];
    const float* bq1  = (const float*)d_in[22];
    const float* Wq2  = (const float*)d_in[23];
    const float* bq2  = (const float*)d_in[24];

    float* ws = (float*)d_ws;
    float* h      = ws;                           // N*64
    float* agg    = h + (size_t)N * 64;           // N*64
    float* part_p = agg + (size_t)N * 64;         // PC*1024
    float* part_c = part_p + (size_t)PC * 1024;   // PC*16
    float* fend   = part_c + PC * 16;
    __hip_bfloat16* Pb     = (__hip_bfloat16*)fend;          // N*1024
    __hip_bfloat16* W2hi   = Pb + (size_t)N * 1024;
    __hip_bfloat16* W2lo   = W2hi + 65536;
    __hip_bfloat16* Wu2hi  = W2lo + 65536;
    __hip_bfloat16* Wu2lo  = Wu2hi + 65536;
    __hip_bfloat16* Wp1hi  = Wu2lo + 65536;
    __hip_bfloat16* Wp1lo  = Wp1hi + 32768;
    __hip_bfloat16* Wp2hi  = Wp1lo + 32768;
    __hip_bfloat16* Wp2lo  = Wp2hi + 32768;
    __hip_bfloat16* Wu1hi  = Wp2lo + 32768;
    __hip_bfloat16* Wu1lo  = Wu1hi + 135168;
    __hip_bfloat16* Wm1phi = Wu1lo + 135168;
    __hip_bfloat16* Wm1plo = Wm1phi + 196608;
    int* hist = (int*)(Wm1plo + 196608);          // NBIN
    int* offs = hist + NBIN;                      // NBIN
    int* perm = offs + NBIN;                      // E

    k_embed<<<N / 4, 256, 0, stream>>>(x, anf, na, W_emb, b_emb, h);
    k_reorder<<<2064, 256, 0, stream>>>(Wm2, Wu2, Wp1, Wp2, Wu1, Wm1,
                                        W2hi, W2lo, Wu2hi, Wu2lo, Wp1hi, Wp1lo,
                                        Wp2hi, Wp2lo, Wu1hi, Wu1lo, Wm1phi, Wm1plo);
    hipMemsetAsync(hist, 0, NBIN * sizeof(int), stream);
    k_hist<<<E / 256, 256, 0, stream>>>(eidx, hist);
    k_scan<<<1, 256, 0, stream>>>(hist, offs);
    k_scatter<<<E / 256, 256, 0, stream>>>(eidx, offs, perm);

    for (int l = 0; l < 2; ++l) {
        k_pre_mfma<<<625, 256, 0, stream>>>(h, anf,
                                            Wm1phi + (size_t)l * 98304, Wm1plo + (size_t)l * 98304,
                                            Pb, agg);
        k_edge<<<E / 128, 256, 0, stream>>>(perm, eidx, ea, amf, Pb,
                                            Wm1 + (size_t)l * 131 * 512, bm1 + l * 64,
                                            W2hi + (size_t)l * 32768, W2lo + (size_t)l * 32768,
                                            bm2 + l * 64, agg);
        k_upd_mfma<<<625, 256, 0, stream>>>(h, anf, na, agg,
                                            Wu1hi + (size_t)l * 67584, Wu1lo + (size_t)l * 67584,
                                            bu1 + l * 64,
                                            Wu2hi + (size_t)l * 32768, Wu2lo + (size_t)l * 32768,
                                            bu2 + l * 64, h);
    }
    k_prepool_mfma<<<625, 256, 0, stream>>>(h, na, batch, Wp1hi, Wp1lo, bp1,
                                            Wp2hi, Wp2lo, bp2, part_p, part_c);
    k_final<<<B, 256, 0, stream>>>(part_p, part_c, Wq1, bq1, Wq2, bq2, (float*)d_out);
}

// Round 8
// 517.434 us; speedup vs baseline: 1.1674x; 1.1674x over previous
//
#include <hip/hip_runtime.h>
#include <hip/hip_bf16.h>
#include <math.h>

// Problem constants
constexpr int N = 10000;
constexpr int E = 160000;
constexpr int B = 16;
constexpr int PC = 625;     // pool partial chunks (= prepool grid)

typedef short bf16x8 __attribute__((ext_vector_type(8)));
typedef float f32x4 __attribute__((ext_vector_type(4)));

__device__ __forceinline__ float silu_f(float x) {
    return x / (1.0f + __expf(-x));
}

// ---------------- K1: embedding h = TP(concat(x,anf), na, W_emb) + b ----------------
__global__ __launch_bounds__(256) void k_embed(
        const float* __restrict__ x, const float* __restrict__ anf,
        const float* __restrict__ na, const float* __restrict__ W,
        const float* __restrict__ b, float* __restrict__ h) {
    int wv = threadIdx.x >> 6;
    int k = threadIdx.x & 63;
    int n = blockIdx.x * 4 + wv;
    float naR[8];
#pragma unroll
    for (int j = 0; j < 8; ++j) naR[j] = na[n * 8 + j];
    float acc = b[k];
#pragma unroll
    for (int i = 0; i < 17; ++i) {
        float xi = (i < 16) ? x[n * 16 + i] : anf[n];
#pragma unroll
        for (int j = 0; j < 8; ++j)
            acc = fmaf(xi * naR[j], W[(i * 8 + j) * 64 + k], acc);
    }
    h[(size_t)n * 64 + k] = acc;
}

// ---------------- fused weight reorder (all 6 reorders in one launch) ----------------
__device__ __forceinline__ void hilo_store(float wv, __hip_bfloat16* hi, __hip_bfloat16* lo, int idx) {
    __hip_bfloat16 hh = __float2bfloat16(wv);
    hi[idx] = hh;
    lo[idx] = __float2bfloat16(wv - __bfloat162float(hh));
}
__device__ __forceinline__ float zr64_val(const float* Wsrc, int idx) {
    int l = idx >> 15;
    int rem = idx & 32767;
    int kk = rem >> 11, nt = (rem >> 9) & 3, c = (rem >> 5) & 15, q = (rem >> 3) & 3, j = rem & 7;
    return Wsrc[(size_t)l * 32768 + (size_t)(kk * 4 + q) * 512 + j * 64 + nt * 16 + c];
}
__device__ __forceinline__ float wu1_val(const float* Wu1, int idx) {
    int l = idx / 67584;
    int rem = idx % 67584;
    int kk = rem / 2048;
    int r2 = rem % 2048;
    int nt = (r2 >> 9) & 3, c = (r2 >> 5) & 15, q = (r2 >> 3) & 3, j = r2 & 7;
    int i = kk * 4 + q;
    return (i < 129) ? Wu1[(size_t)l * 129 * 512 + (size_t)i * 512 + j * 64 + nt * 16 + c] : 0.f;
}
__device__ __forceinline__ float wm1p_val(const float* Wm1, int idx) {
    int l = idx / 98304;
    int rem = idx % 98304;
    int kk = rem / 32768;
    int r2 = rem % 32768;
    int nt = (r2 >> 9) & 63, c = (r2 >> 5) & 15, q = (r2 >> 3) & 3, t = r2 & 7;
    int i = kk * 32 + q * 8 + t;
    int col = nt * 16 + c;
    int part = col >> 9, kd = (col >> 3) & 63, j = col & 7;
    if (i >= 65) return 0.f;
    return Wm1[(size_t)l * 131 * 512 + (size_t)(part ? 65 + i : i) * 512 + j * 64 + kd];
}
__global__ __launch_bounds__(256) void k_reorder(
        const float* __restrict__ Wm2, const float* __restrict__ Wu2,
        const float* __restrict__ Wp1, const float* __restrict__ Wp2,
        const float* __restrict__ Wu1, const float* __restrict__ Wm1,
        __hip_bfloat16* W2hi, __hip_bfloat16* W2lo,
        __hip_bfloat16* Wu2hi, __hip_bfloat16* Wu2lo,
        __hip_bfloat16* Wp1hi, __hip_bfloat16* Wp1lo,
        __hip_bfloat16* Wp2hi, __hip_bfloat16* Wp2lo,
        __hip_bfloat16* Wu1hi, __hip_bfloat16* Wu1lo,
        __hip_bfloat16* Wm1phi, __hip_bfloat16* Wm1plo) {
    int idx = blockIdx.x * 256 + threadIdx.x;
    if (idx < 65536)        hilo_store(zr64_val(Wm2, idx), W2hi, W2lo, idx);
    else if (idx < 131072) { int i2 = idx - 65536;  hilo_store(zr64_val(Wu2, i2), Wu2hi, Wu2lo, i2); }
    else if (idx < 163840) { int i2 = idx - 131072; hilo_store(zr64_val(Wp1, i2), Wp1hi, Wp1lo, i2); }
    else if (idx < 196608) { int i2 = idx - 163840; hilo_store(zr64_val(Wp2, i2), Wp2hi, Wp2lo, i2); }
    else if (idx < 331776) { int i2 = idx - 196608; hilo_store(wu1_val(Wu1, i2), Wu1hi, Wu1lo, i2); }
    else if (idx < 528384) { int i2 = idx - 331776; hilo_store(wm1p_val(Wm1, i2), Wm1phi, Wm1plo, i2); }
}

// ---------------- K2: precompute P = ha @ B (MFMA, 16 nodes, 4 waves split Nout) + zero agg ----------------
__global__ __launch_bounds__(256) void k_pre_mfma(
        const float* __restrict__ h, const float* __restrict__ anf,
        const __hip_bfloat16* __restrict__ Bhi, const __hip_bfloat16* __restrict__ Blo,
        __hip_bfloat16* __restrict__ P, float* __restrict__ agg) {
    __shared__ __align__(16) __hip_bfloat16 ha_s[16 * 96];
    int tid = threadIdx.x;
    int w = tid >> 6, l = tid & 63;
    int n0 = blockIdx.x * 16;
    // zero this block's slice of agg (625*1024 == N*64)
    float4 z4 = {0.f, 0.f, 0.f, 0.f};
    ((float4*)(agg + (size_t)blockIdx.x * 1024))[tid] = z4;
    for (int idx = tid; idx < 16 * 96; idx += 256) {
        int r = idx / 96, c = idx % 96;
        float v = (c < 64) ? h[(size_t)(n0 + r) * 64 + c] : (c == 64 ? anf[n0 + r] : 0.f);
        ha_s[idx] = __float2bfloat16(v);
    }
    __syncthreads();
    int c16 = l & 15, q = l >> 4;
    bf16x8 aF[3];
#pragma unroll
    for (int kk = 0; kk < 3; ++kk)
        aF[kk] = *(const bf16x8*)&ha_s[c16 * 96 + kk * 32 + q * 8];
    int lofs = (c16 * 4 + q) * 8;
    f32x4 zero4 = {0.f, 0.f, 0.f, 0.f};
#pragma unroll
    for (int ntg = 0; ntg < 2; ++ntg) {
        f32x4 acc[8];
#pragma unroll
        for (int t = 0; t < 8; ++t) acc[t] = zero4;
#pragma unroll
        for (int kk = 0; kk < 3; ++kk) {
#pragma unroll
            for (int nt2 = 0; nt2 < 8; ++nt2) {
                int nt = w * 16 + ntg * 8 + nt2;
                bf16x8 bh = *(const bf16x8*)(Bhi + (size_t)(kk * 64 + nt) * 512 + lofs);
                bf16x8 bl = *(const bf16x8*)(Blo + (size_t)(kk * 64 + nt) * 512 + lofs);
                acc[nt2] = __builtin_amdgcn_mfma_f32_16x16x32_bf16(aF[kk], bh, acc[nt2], 0, 0, 0);
                acc[nt2] = __builtin_amdgcn_mfma_f32_16x16x32_bf16(aF[kk], bl, acc[nt2], 0, 0, 0);
            }
        }
#pragma unroll
        for (int nt2 = 0; nt2 < 8; ++nt2)
#pragma unroll
            for (int r = 0; r < 4; ++r) {
                int n = n0 + q * 4 + r;
                P[(size_t)n * 1024 + (w * 16 + ntg * 8 + nt2) * 16 + c16] = __float2bfloat16(acc[nt2][r]);
            }
    }
}

// ---------------- K3: edge kernel (R5 structure, phase-1 8-edge register staging) ----------------
constexpr int MS = 72;
__global__ __launch_bounds__(256, 3) void k_edge(
        const int* __restrict__ eidx, const float* __restrict__ ea,
        const float* __restrict__ amf, const __hip_bfloat16* __restrict__ P,
        const float* __restrict__ Wm1_l, const float* __restrict__ bm1_l,
        const __hip_bfloat16* __restrict__ W2hi, const __hip_bfloat16* __restrict__ W2lo,
        const float* __restrict__ bm2_l, float* __restrict__ agg) {
    __shared__ __align__(16) __hip_bfloat16 m_s[128 * MS];
    __shared__ float ea_s[128][9];
    __shared__ float amf_s[128];
    __shared__ int src_s[128], dst_s[128];
    __shared__ float bm1_s[64], bm2_s[64];
    int tid = threadIdx.x;
    int l = tid & 63, w = tid >> 6;
    int e0 = blockIdx.x * 128;
    for (int idx = tid; idx < 128; idx += 256) {
        src_s[idx] = eidx[e0 + idx];
        dst_s[idx] = eidx[E + e0 + idx];
        amf_s[idx] = amf[e0 + idx];
    }
    for (int idx = tid; idx < 1024; idx += 256) ea_s[idx >> 3][idx & 7] = ea[(size_t)e0 * 8 + idx];
    if (tid < 64) { bm1_s[tid] = bm1_l[tid]; bm2_s[tid] = bm2_l[tid]; }
    float w130R[8];
#pragma unroll
    for (int j = 0; j < 8; ++j) w130R[j] = Wm1_l[130 * 512 + j * 64 + l];
    __syncthreads();

    // ---- phase 1: m = bf16(silu(m1)); 8-edge register-staged gathers for load overlap ----
    float bm1k = bm1_s[l];
    for (int q0 = 0; q0 < 32; q0 += 8) {
        bf16x8 p1r[8], p2r[8];
#pragma unroll
        for (int t = 0; t < 8; ++t) {
            int le = w * 32 + q0 + t;
            p1r[t] = *(const bf16x8*)(P + (size_t)dst_s[le] * 1024 + l * 8);
            p2r[t] = *(const bf16x8*)(P + (size_t)src_s[le] * 1024 + 512 + l * 8);
        }
#pragma unroll
        for (int t = 0; t < 8; ++t) {
            int le = w * 32 + q0 + t;
            float amfe = amf_s[le];
            float macc = bm1k;
#pragma unroll
            for (int j = 0; j < 8; ++j) {
                union { short s; __hip_bfloat16 b; } u1c, u2c;
                u1c.s = p1r[t][j]; u2c.s = p2r[t][j];
                float s = __bfloat162float(u1c.b) + __bfloat162float(u2c.b) + amfe * w130R[j];
                macc = fmaf(ea_s[le][j], s, macc);
            }
            m_s[le * MS + l] = __float2bfloat16(silu_f(macc));
        }
    }
    __syncthreads();

    // ---- phase 2: z-GEMM  D[e][kd] = sum_ij (m[e][i]*ea[e][j]) * W2flat[ij][kd] ----
    int c16 = l & 15, q = l >> 4;
    int e0w = w * 32;
    float eaA[2][8];
#pragma unroll
    for (int mt = 0; mt < 2; ++mt)
#pragma unroll
        for (int j = 0; j < 8; ++j) eaA[mt][j] = ea_s[e0w + mt * 16 + c16][j];

    f32x4 acc[2][4];
    f32x4 zero4 = {0.f, 0.f, 0.f, 0.f};
#pragma unroll
    for (int mt = 0; mt < 2; ++mt)
#pragma unroll
        for (int nt = 0; nt < 4; ++nt) acc[mt][nt] = zero4;

    int lofs = (c16 * 4 + q) * 8;
#pragma unroll 2
    for (int kk = 0; kk < 16; ++kk) {
        bf16x8 bh[4], bl[4];
#pragma unroll
        for (int nt = 0; nt < 4; ++nt) {
            int off = (kk * 4 + nt) * 512 + lofs;
            bh[nt] = *(const bf16x8*)(W2hi + off);
            bl[nt] = *(const bf16x8*)(W2lo + off);
        }
#pragma unroll
        for (int mt = 0; mt < 2; ++mt) {
            float mv = __bfloat162float(m_s[(e0w + mt * 16 + c16) * MS + kk * 4 + q]);
            union { bf16x8 v; __hip_bfloat16 h[8]; } au;
#pragma unroll
            for (int j = 0; j < 8; ++j) au.h[j] = __float2bfloat16(mv * eaA[mt][j]);
#pragma unroll
            for (int nt = 0; nt < 4; ++nt) {
                acc[mt][nt] = __builtin_amdgcn_mfma_f32_16x16x32_bf16(au.v, bh[nt], acc[mt][nt], 0, 0, 0);
                acc[mt][nt] = __builtin_amdgcn_mfma_f32_16x16x32_bf16(au.v, bl[nt], acc[mt][nt], 0, 0, 0);
            }
        }
    }
#pragma unroll
    for (int mt = 0; mt < 2; ++mt)
#pragma unroll
        for (int nt = 0; nt < 4; ++nt) {
            int kd = nt * 16 + c16;
            float bias = bm2_s[kd];
#pragma unroll
            for (int r = 0; r < 4; ++r) {
                int e = e0w + mt * 16 + q * 4 + r;
                float v = silu_f(bias + acc[mt][nt][r]);
                atomicAdd(&agg[(size_t)dst_s[e] * 64 + kd], v);
            }
        }
}

// ---------------- K4: node update, fused z-GEMMs, 4 waves split K + LDS reduce ----------------
__global__ __launch_bounds__(256) void k_upd_mfma(
        const float* __restrict__ h_in, const float* __restrict__ anf,
        const float* __restrict__ na, const float* __restrict__ agg,
        const __hip_bfloat16* __restrict__ W1hi, const __hip_bfloat16* __restrict__ W1lo,
        const float* __restrict__ bu1_l,
        const __hip_bfloat16* __restrict__ W2hi_, const __hip_bfloat16* __restrict__ W2lo_,
        const float* __restrict__ bu2_l,
        float* __restrict__ h) {
    __shared__ __align__(16) __hip_bfloat16 xa_s[16 * 136];
    __shared__ __align__(16) __hip_bfloat16 u1_s[16 * 72];
    __shared__ float part_s[4][16][64];
    int tid = threadIdx.x;
    int w = tid >> 6, l = tid & 63;
    int n0 = blockIdx.x * 16;
    for (int idx = tid; idx < 16 * 132; idx += 256) {
        int r = idx / 132, c = idx % 132;
        int n = n0 + r;
        float v;
        if (c < 64) v = h_in[(size_t)n * 64 + c];
        else if (c == 64) v = anf[n];
        else if (c < 129) v = agg[(size_t)n * 64 + (c - 65)];
        else v = 0.f;
        xa_s[r * 136 + c] = __float2bfloat16(v);
    }
    int c16 = l & 15, q = l >> 4;
    float naA[8];
#pragma unroll
    for (int j = 0; j < 8; ++j) naA[j] = na[(size_t)(n0 + c16) * 8 + j];
    __syncthreads();
    int lofs = (c16 * 4 + q) * 8;
    f32x4 zero4 = {0.f, 0.f, 0.f, 0.f};
    f32x4 acc[4];
#pragma unroll
    for (int nt = 0; nt < 4; ++nt) acc[nt] = zero4;
    for (int kk = w; kk < 33; kk += 4) {
        bf16x8 bh[4], bl[4];
#pragma unroll
        for (int nt = 0; nt < 4; ++nt) {
            int off = (kk * 4 + nt) * 512 + lofs;
            bh[nt] = *(const bf16x8*)(W1hi + off);
            bl[nt] = *(const bf16x8*)(W1lo + off);
        }
        float mv = __bfloat162float(xa_s[c16 * 136 + kk * 4 + q]);
        union { bf16x8 v; __hip_bfloat16 hx[8]; } au;
#pragma unroll
        for (int j = 0; j < 8; ++j) au.hx[j] = __float2bfloat16(mv * naA[j]);
#pragma unroll
        for (int nt = 0; nt < 4; ++nt) {
            acc[nt] = __builtin_amdgcn_mfma_f32_16x16x32_bf16(au.v, bh[nt], acc[nt], 0, 0, 0);
            acc[nt] = __builtin_amdgcn_mfma_f32_16x16x32_bf16(au.v, bl[nt], acc[nt], 0, 0, 0);
        }
    }
#pragma unroll
    for (int nt = 0; nt < 4; ++nt)
#pragma unroll
        for (int r = 0; r < 4; ++r) part_s[w][q * 4 + r][nt * 16 + c16] = acc[nt][r];
    __syncthreads();
    for (int t = tid; t < 1024; t += 256) {
        int row = t >> 6, col = t & 63;
        float v = part_s[0][row][col] + part_s[1][row][col] + part_s[2][row][col] +
                  part_s[3][row][col] + bu1_l[col];
        u1_s[row * 72 + col] = __float2bfloat16(silu_f(v));
    }
    __syncthreads();
    f32x4 acc2[4];
#pragma unroll
    for (int nt = 0; nt < 4; ++nt) acc2[nt] = zero4;
    for (int kk = w; kk < 16; kk += 4) {
        bf16x8 bh[4], bl[4];
#pragma unroll
        for (int nt = 0; nt < 4; ++nt) {
            int off = (kk * 4 + nt) * 512 + lofs;
            bh[nt] = *(const bf16x8*)(W2hi_ + off);
            bl[nt] = *(const bf16x8*)(W2lo_ + off);
        }
        float mv = __bfloat162float(u1_s[c16 * 72 + kk * 4 + q]);
        union { bf16x8 v; __hip_bfloat16 hx[8]; } au;
#pragma unroll
        for (int j = 0; j < 8; ++j) au.hx[j] = __float2bfloat16(mv * naA[j]);
#pragma unroll
        for (int nt = 0; nt < 4; ++nt) {
            acc2[nt] = __builtin_amdgcn_mfma_f32_16x16x32_bf16(au.v, bh[nt], acc2[nt], 0, 0, 0);
            acc2[nt] = __builtin_amdgcn_mfma_f32_16x16x32_bf16(au.v, bl[nt], acc2[nt], 0, 0, 0);
        }
    }
    __syncthreads();
#pragma unroll
    for (int nt = 0; nt < 4; ++nt)
#pragma unroll
        for (int r = 0; r < 4; ++r) part_s[w][q * 4 + r][nt * 16 + c16] = acc2[nt][r];
    __syncthreads();
    for (int t = tid; t < 1024; t += 256) {
        int row = t >> 6, col = t & 63;
        float v = part_s[0][row][col] + part_s[1][row][col] + part_s[2][row][col] +
                  part_s[3][row][col] + bu2_l[col];
        h[(size_t)(n0 + row) * 64 + col] += v;
    }
}

// ---------------- K6: prepool, fused z-GEMMs + in-block pooling (4-wave K-split) ----------------
__global__ __launch_bounds__(256) void k_prepool_mfma(
        const float* __restrict__ h, const float* __restrict__ na,
        const int* __restrict__ batch,
        const __hip_bfloat16* __restrict__ W1hi, const __hip_bfloat16* __restrict__ W1lo,
        const float* __restrict__ bp1,
        const __hip_bfloat16* __restrict__ W2hi_, const __hip_bfloat16* __restrict__ W2lo_,
        const float* __restrict__ bp2,
        float* __restrict__ partial_p, float* __restrict__ partial_cnt) {
    __shared__ __align__(16) __hip_bfloat16 xa_s[16 * 72];
    __shared__ __align__(16) __hip_bfloat16 u1_s[16 * 72];
    __shared__ float part_s[4][16][64];
    __shared__ float pool_s[16][64];
    __shared__ float cnt_s[16];
    __shared__ int batch_s[16];
    int tid = threadIdx.x;
    int w = tid >> 6, l = tid & 63;
    int n0 = blockIdx.x * 16;
    for (int idx = tid; idx < 1024; idx += 256) pool_s[idx >> 6][idx & 63] = 0.f;
    if (tid < 16) { cnt_s[tid] = 0.f; batch_s[tid] = batch[n0 + tid]; }
    for (int idx = tid; idx < 16 * 64; idx += 256) {
        int r = idx >> 6, c = idx & 63;
        xa_s[r * 72 + c] = __float2bfloat16(h[(size_t)(n0 + r) * 64 + c]);
    }
    int c16 = l & 15, q = l >> 4;
    float naA[8];
#pragma unroll
    for (int j = 0; j < 8; ++j) naA[j] = na[(size_t)(n0 + c16) * 8 + j];
    __syncthreads();
    if (tid < 16) atomicAdd(&cnt_s[batch_s[tid]], 1.0f);
    int lofs = (c16 * 4 + q) * 8;
    f32x4 zero4 = {0.f, 0.f, 0.f, 0.f};
    f32x4 acc[4];
#pragma unroll
    for (int nt = 0; nt < 4; ++nt) acc[nt] = zero4;
    for (int kk = w; kk < 16; kk += 4) {
        bf16x8 bh[4], bl[4];
#pragma unroll
        for (int nt = 0; nt < 4; ++nt) {
            int off = (kk * 4 + nt) * 512 + lofs;
            bh[nt] = *(const bf16x8*)(W1hi + off);
            bl[nt] = *(const bf16x8*)(W1lo + off);
        }
        float mv = __bfloat162float(xa_s[c16 * 72 + kk * 4 + q]);
        union { bf16x8 v; __hip_bfloat16 hx[8]; } au;
#pragma unroll
        for (int j = 0; j < 8; ++j) au.hx[j] = __float2bfloat16(mv * naA[j]);
#pragma unroll
        for (int nt = 0; nt < 4; ++nt) {
            acc[nt] = __builtin_amdgcn_mfma_f32_16x16x32_bf16(au.v, bh[nt], acc[nt], 0, 0, 0);
            acc[nt] = __builtin_amdgcn_mfma_f32_16x16x32_bf16(au.v, bl[nt], acc[nt], 0, 0, 0);
        }
    }
#pragma unroll
    for (int nt = 0; nt < 4; ++nt)
#pragma unroll
        for (int r = 0; r < 4; ++r) part_s[w][q * 4 + r][nt * 16 + c16] = acc[nt][r];
    __syncthreads();
    for (int t = tid; t < 1024; t += 256) {
        int row = t >> 6, col = t & 63;
        float v = part_s[0][row][col] + part_s[1][row][col] + part_s[2][row][col] +
                  part_s[3][row][col] + bp1[col];
        u1_s[row * 72 + col] = __float2bfloat16(silu_f(v));
    }
    __syncthreads();
    f32x4 acc2[4];
#pragma unroll
    for (int nt = 0; nt < 4; ++nt) acc2[nt] = zero4;
    for (int kk = w; kk < 16; kk += 4) {
        bf16x8 bh[4], bl[4];
#pragma unroll
        for (int nt = 0; nt < 4; ++nt) {
            int off = (kk * 4 + nt) * 512 + lofs;
            bh[nt] = *(const bf16x8*)(W2hi_ + off);
            bl[nt] = *(const bf16x8*)(W2lo_ + off);
        }
        float mv = __bfloat162float(u1_s[c16 * 72 + kk * 4 + q]);
        union { bf16x8 v; __hip_bfloat16 hx[8]; } au;
#pragma unroll
        for (int j = 0; j < 8; ++j) au.hx[j] = __float2bfloat16(mv * naA[j]);
#pragma unroll
        for (int nt = 0; nt < 4; ++nt) {
            acc2[nt] = __builtin_amdgcn_mfma_f32_16x16x32_bf16(au.v, bh[nt], acc2[nt], 0, 0, 0);
            acc2[nt] = __builtin_amdgcn_mfma_f32_16x16x32_bf16(au.v, bl[nt], acc2[nt], 0, 0, 0);
        }
    }
    __syncthreads();
#pragma unroll
    for (int nt = 0; nt < 4; ++nt)
#pragma unroll
        for (int r = 0; r < 4; ++r) part_s[w][q * 4 + r][nt * 16 + c16] = acc2[nt][r];
    __syncthreads();
    for (int t = tid; t < 1024; t += 256) {
        int row = t >> 6, col = t & 63;
        float v = part_s[0][row][col] + part_s[1][row][col] + part_s[2][row][col] +
                  part_s[3][row][col] + bp2[col];
        atomicAdd(&pool_s[batch_s[row]][col], v);
    }
    __syncthreads();
    for (int t = tid; t < 1024; t += 256)
        partial_p[(size_t)blockIdx.x * 1024 + t] = pool_s[t >> 6][t & 63];
    if (tid < 16) partial_cnt[blockIdx.x * 16 + tid] = cnt_s[tid];
}

// ---------------- K7: reduce 625 partials, mean, final MLP (one block per graph) ----------------
__global__ __launch_bounds__(256) void k_final(
        const float* __restrict__ partial_p, const float* __restrict__ partial_cnt,
        const float* __restrict__ Wq1, const float* __restrict__ bq1,
        const float* __restrict__ Wq2, const float* __restrict__ bq2,
        float* __restrict__ out) {
    __shared__ float red[4][64];
    __shared__ float cred[4];
    __shared__ float g_s[64];
    int b = blockIdx.x;
    int tid = threadIdx.x;
    int k = tid & 63, part = tid >> 6;
    float s = 0.f;
    for (int c = part; c < PC; c += 4) s += partial_p[(size_t)c * 1024 + b * 64 + k];
    red[part][k] = s;
    if (k == 0) {
        float cc = 0.f;
        for (int c = part; c < PC; c += 4) cc += partial_cnt[c * 16 + b];
        cred[part] = cc;
    }
    __syncthreads();
    if (tid < 64) {
        float cnt = cred[0] + cred[1] + cred[2] + cred[3];
        g_s[k] = (red[0][k] + red[1][k] + red[2][k] + red[3][k]) / fmaxf(cnt, 1.0f);
    }
    __syncthreads();
    if (tid < 64) {
        float acc = bq1[k];
#pragma unroll
        for (int i = 0; i < 64; ++i) acc = fmaf(g_s[i], Wq1[i * 64 + k], acc);
        float v = silu_f(acc) * Wq2[k];
#pragma unroll
        for (int off = 32; off > 0; off >>= 1) v += __shfl_down(v, off, 64);
        if (k == 0) out[b] = v + bq2[0];
    }
}

extern "C" void kernel_launch(void* const* d_in, const int* in_sizes, int n_in,
                              void* d_out, int out_size, void* d_ws, size_t ws_size,
                              hipStream_t stream) {
    const float* x    = (const float*)d_in[0];
    const int*   eidx = (const int*)  d_in[1];
    const float* ea   = (const float*)d_in[2];
    const float* na   = (const float*)d_in[3];
    const float* amf  = (const float*)d_in[4];
    const float* anf  = (const float*)d_in[5];
    const int*   batch= (const int*)  d_in[6];
    const float* W_emb= (const float*)d_in[7];
    const float* b_emb= (const float*)d_in[8];
    const float* Wm1  = (const float*)d_in[9];
    const float* bm1  = (const float*)d_in[10];
    const float* Wm2  = (const float*)d_in[11];
    const float* bm2  = (const float*)d_in[12];
    const float* Wu1  = (const float*)d_in[13];
    const float* bu1  = (const float*)d_in[14];
    const float* Wu2  = (const float*)d_in[15];
    const float* bu2  = (const float*)d_in[16];
    const float* Wp1  = (const float*)d_in[17];
    const float* bp1  = (const float*)d_in[18];
    const float* Wp2  = (const float*)d_in[19];
    const float* bp2  = (const float*)d_in[20];
    const float* Wq1  = (const float*)d_in[21];
    const float* bq1  = (const float*)d_in[22];
    const float* Wq2  = (const float*)d_in[23];
    const float* bq2  = (const float*)d_in[24];

    float* ws = (float*)d_ws;
    float* h      = ws;                           // N*64
    float* agg    = h + (size_t)N * 64;           // N*64
    float* part_p = agg + (size_t)N * 64;         // PC*1024
    float* part_c = part_p + (size_t)PC * 1024;   // PC*16
    float* fend   = part_c + PC * 16;
    __hip_bfloat16* Pb     = (__hip_bfloat16*)fend;          // N*1024
    __hip_bfloat16* W2hi   = Pb + (size_t)N * 1024;
    __hip_bfloat16* W2lo   = W2hi + 65536;
    __hip_bfloat16* Wu2hi  = W2lo + 65536;
    __hip_bfloat16* Wu2lo  = Wu2hi + 65536;
    __hip_bfloat16* Wp1hi  = Wu2lo + 65536;
    __hip_bfloat16* Wp1lo  = Wp1hi + 32768;
    __hip_bfloat16* Wp2hi  = Wp1lo + 32768;
    __hip_bfloat16* Wp2lo  = Wp2hi + 32768;
    __hip_bfloat16* Wu1hi  = Wp2lo + 32768;
    __hip_bfloat16* Wu1lo  = Wu1hi + 135168;
    __hip_bfloat16* Wm1phi = Wu1lo + 135168;
    __hip_bfloat16* Wm1plo = Wm1phi + 196608;

    k_embed<<<N / 4, 256, 0, stream>>>(x, anf, na, W_emb, b_emb, h);
    k_reorder<<<2064, 256, 0, stream>>>(Wm2, Wu2, Wp1, Wp2, Wu1, Wm1,
                                        W2hi, W2lo, Wu2hi, Wu2lo, Wp1hi, Wp1lo,
                                        Wp2hi, Wp2lo, Wu1hi, Wu1lo, Wm1phi, Wm1plo);

    for (int l = 0; l < 2; ++l) {
        k_pre_mfma<<<625, 256, 0, stream>>>(h, anf,
                                            Wm1phi + (size_t)l * 98304, Wm1plo + (size_t)l * 98304,
                                            Pb, agg);
        k_edge<<<E / 128, 256, 0, stream>>>(eidx, ea, amf, Pb,
                                            Wm1 + (size_t)l * 131 * 512, bm1 + l * 64,
                                            W2hi + (size_t)l * 32768, W2lo + (size_t)l * 32768,
                                            bm2 + l * 64, agg);
        k_upd_mfma<<<625, 256, 0, stream>>>(h, anf, na, agg,
                                            Wu1hi + (size_t)l * 67584, Wu1lo + (size_t)l * 67584,
                                            bu1 + l * 64,
                                            Wu2hi + (size_t)l * 32768, Wu2lo + (size_t)l * 32768,
                                            bu2 + l * 64, h);
    }
    k_prepool_mfma<<<625, 256, 0, stream>>>(h, na, batch, Wp1hi, Wp1lo, bp1,
                                            Wp2hi, Wp2lo, bp2, part_p, part_c);
    k_final<<<B, 256, 0, stream>>>(part_p, part_c, Wq1, bq1, Wq2, bq2, (float*)d_out);
}

// Round 9
// 435.630 us; speedup vs baseline: 1.3866x; 1.1878x over previous
//
#include <hip/hip_runtime.h>
#include <hip/hip_bf16.h>
#include <math.h>

// Problem constants
constexpr int N = 10000;
constexpr int E = 160000;
constexpr int B = 16;
constexpr int POOL_CHUNKS = 80;   // 80 * 125 = 10000

typedef short bf16x8 __attribute__((ext_vector_type(8)));
typedef float f32x4 __attribute__((ext_vector_type(4)));

__device__ __forceinline__ float silu_f(float x) {
    return x / (1.0f + __expf(-x));
}

// ---------------- weight reorders (R5-proven, 6 launches) ----------------
__global__ __launch_bounds__(256) void k_w2(
        const float* __restrict__ Wsrc,
        __hip_bfloat16* __restrict__ Whi, __hip_bfloat16* __restrict__ Wlo) {
    int idx = blockIdx.x * 256 + threadIdx.x;
    int l = idx >> 15;
    int rem = idx & 32767;
    int kk = rem >> 11;
    int nt = (rem >> 9) & 3;
    int c  = (rem >> 5) & 15;
    int q  = (rem >> 3) & 3;
    int j  = rem & 7;
    int i = kk * 4 + q;
    int k = nt * 16 + c;
    float wv = Wsrc[(size_t)l * 32768 + i * 512 + j * 64 + k];
    __hip_bfloat16 hi = __float2bfloat16(wv);
    Whi[idx] = hi;
    Wlo[idx] = __float2bfloat16(wv - __bfloat162float(hi));
}

__global__ __launch_bounds__(256) void k_wu1(
        const float* __restrict__ Wu1,
        __hip_bfloat16* __restrict__ Whi, __hip_bfloat16* __restrict__ Wlo) {
    int idx = blockIdx.x * 256 + threadIdx.x;    // 2 * 67584
    int l = idx / 67584;
    int rem = idx % 67584;
    int kk = rem / 2048;          // 0..32
    int r2 = rem % 2048;
    int nt = (r2 >> 9) & 3;
    int c  = (r2 >> 5) & 15;
    int q  = (r2 >> 3) & 3;
    int j  = r2 & 7;
    int i = kk * 4 + q;           // 0..131
    float wv = (i < 129) ? Wu1[(size_t)l * 129 * 512 + i * 512 + j * 64 + nt * 16 + c] : 0.f;
    __hip_bfloat16 hi = __float2bfloat16(wv);
    Whi[idx] = hi;
    Wlo[idx] = __float2bfloat16(wv - __bfloat162float(hi));
}

// plain B reorder for precompute GEMM; storage column col = part*512 + kd*8 + j
__global__ __launch_bounds__(256) void k_wm1p(
        const float* __restrict__ Wm1,
        __hip_bfloat16* __restrict__ Whi, __hip_bfloat16* __restrict__ Wlo) {
    int idx = blockIdx.x * 256 + threadIdx.x;    // 2 * 98304
    int l = idx / 98304;
    int rem = idx % 98304;
    int kk = rem / 32768;         // 0..2
    int r2 = rem % 32768;
    int nt = (r2 >> 9) & 63;
    int c  = (r2 >> 5) & 15;
    int q  = (r2 >> 3) & 3;
    int t  = r2 & 7;
    int i = kk * 32 + q * 8 + t;  // 0..95
    int col = nt * 16 + c;        // 0..1023
    int part = col >> 9, kd = (col >> 3) & 63, j = col & 7;
    float wv = 0.f;
    if (i < 65)
        wv = Wm1[(size_t)l * 131 * 512 + (size_t)(part ? 65 + i : i) * 512 + j * 64 + kd];
    __hip_bfloat16 hi = __float2bfloat16(wv);
    Whi[idx] = hi;
    Wlo[idx] = __float2bfloat16(wv - __bfloat162float(hi));
}

// ---------------- device helper: P-GEMM body (R5 k_pre, reads ha_s[16*96]) ----------------
__device__ __forceinline__ void pre_gemm_body(
        const __hip_bfloat16* ha_s, int w, int l,
        const __hip_bfloat16* __restrict__ Bhi, const __hip_bfloat16* __restrict__ Blo,
        __hip_bfloat16* __restrict__ P, int n0) {
    int c16 = l & 15, q = l >> 4;
    bf16x8 aF[3];
#pragma unroll
    for (int kk = 0; kk < 3; ++kk)
        aF[kk] = *(const bf16x8*)&ha_s[c16 * 96 + kk * 32 + q * 8];
    int lofs = (c16 * 4 + q) * 8;
    f32x4 zero4 = {0.f, 0.f, 0.f, 0.f};
#pragma unroll
    for (int ntg = 0; ntg < 2; ++ntg) {
        f32x4 acc[8];
#pragma unroll
        for (int t = 0; t < 8; ++t) acc[t] = zero4;
#pragma unroll
        for (int kk = 0; kk < 3; ++kk) {
#pragma unroll
            for (int nt2 = 0; nt2 < 8; ++nt2) {
                int nt = w * 16 + ntg * 8 + nt2;
                bf16x8 bh = *(const bf16x8*)(Bhi + (size_t)(kk * 64 + nt) * 512 + lofs);
                bf16x8 bl = *(const bf16x8*)(Blo + (size_t)(kk * 64 + nt) * 512 + lofs);
                acc[nt2] = __builtin_amdgcn_mfma_f32_16x16x32_bf16(aF[kk], bh, acc[nt2], 0, 0, 0);
                acc[nt2] = __builtin_amdgcn_mfma_f32_16x16x32_bf16(aF[kk], bl, acc[nt2], 0, 0, 0);
            }
        }
#pragma unroll
        for (int nt2 = 0; nt2 < 8; ++nt2)
#pragma unroll
            for (int r = 0; r < 4; ++r) {
                int n = n0 + q * 4 + r;
                P[(size_t)n * 1024 + (w * 16 + ntg * 8 + nt2) * 16 + c16] = __float2bfloat16(acc[nt2][r]);
            }
    }
}

// ---------------- device helper: one z-GEMM stage, 4 waves split K, result into part_s ----------------
__device__ __forceinline__ void zgemm_stage(
        const __hip_bfloat16* xsrc, int xstride, int kkmax, int w, int c16, int q, int lofs,
        const float* naA,
        const __hip_bfloat16* __restrict__ Whi, const __hip_bfloat16* __restrict__ Wlo,
        float (*part_s)[16][64]) {
    f32x4 zero4 = {0.f, 0.f, 0.f, 0.f};
    f32x4 acc[4];
#pragma unroll
    for (int nt = 0; nt < 4; ++nt) acc[nt] = zero4;
    for (int kk = w; kk < kkmax; kk += 4) {
        bf16x8 bh[4], bl[4];
#pragma unroll
        for (int nt = 0; nt < 4; ++nt) {
            int off = (kk * 4 + nt) * 512 + lofs;
            bh[nt] = *(const bf16x8*)(Whi + off);
            bl[nt] = *(const bf16x8*)(Wlo + off);
        }
        float mv = __bfloat162float(xsrc[c16 * xstride + kk * 4 + q]);
        union { bf16x8 v; __hip_bfloat16 hx[8]; } au;
#pragma unroll
        for (int j = 0; j < 8; ++j) au.hx[j] = __float2bfloat16(mv * naA[j]);
#pragma unroll
        for (int nt = 0; nt < 4; ++nt) {
            acc[nt] = __builtin_amdgcn_mfma_f32_16x16x32_bf16(au.v, bh[nt], acc[nt], 0, 0, 0);
            acc[nt] = __builtin_amdgcn_mfma_f32_16x16x32_bf16(au.v, bl[nt], acc[nt], 0, 0, 0);
        }
    }
#pragma unroll
    for (int nt = 0; nt < 4; ++nt)
#pragma unroll
        for (int r = 0; r < 4; ++r) part_s[w][q * 4 + r][nt * 16 + c16] = acc[nt][r];
}

// ---------------- K1: fused embed + P(layer0) + agg zero ----------------
__global__ __launch_bounds__(256) void k_embed_pre(
        const float* __restrict__ x, const float* __restrict__ anf,
        const float* __restrict__ na, const float* __restrict__ W_emb,
        const float* __restrict__ b_emb,
        const __hip_bfloat16* __restrict__ Bhi, const __hip_bfloat16* __restrict__ Blo,
        float* __restrict__ h, __hip_bfloat16* __restrict__ P, float* __restrict__ agg) {
    __shared__ float xs[16][18];
    __shared__ float na_s[16][8];
    __shared__ __align__(16) __hip_bfloat16 ha_s[16 * 96];
    int tid = threadIdx.x, w = tid >> 6, l = tid & 63;
    int n0 = blockIdx.x * 16;
    {
        int r = tid >> 4, c = tid & 15;
        xs[r][c] = x[(size_t)(n0 + r) * 16 + c];
    }
    if (tid < 16) xs[tid][16] = anf[n0 + tid];
    if (tid < 128) na_s[tid >> 3][tid & 7] = na[(size_t)n0 * 8 + tid];
    // zero agg slice (each block owns its 16-node slice; agg unread here)
    float4 z4 = {0.f, 0.f, 0.f, 0.f};
    ((float4*)(agg + (size_t)blockIdx.x * 1024))[tid] = z4;
    __syncthreads();
    // embed: wave w handles nodes w*4..w*4+3, lane l = output dim k
    float acc[4];
#pragma unroll
    for (int t = 0; t < 4; ++t) acc[t] = b_emb[l];
    for (int i = 0; i < 17; ++i) {
#pragma unroll
        for (int j = 0; j < 8; ++j) {
            float wv = W_emb[(i * 8 + j) * 64 + l];
#pragma unroll
            for (int t = 0; t < 4; ++t) {
                int nn = w * 4 + t;
                acc[t] = fmaf(xs[nn][i] * na_s[nn][j], wv, acc[t]);
            }
        }
    }
#pragma unroll
    for (int t = 0; t < 4; ++t) {
        int nn = w * 4 + t;
        h[(size_t)(n0 + nn) * 64 + l] = acc[t];
        ha_s[nn * 96 + l] = __float2bfloat16(acc[t]);
    }
    if (tid < 16) ha_s[tid * 96 + 64] = __float2bfloat16(xs[tid][16]);
    for (int idx = tid; idx < 16 * 31; idx += 256) {
        int r = idx / 31, c = 65 + idx % 31;
        ha_s[r * 96 + c] = __float2bfloat16(0.f);
    }
    __syncthreads();
    pre_gemm_body(ha_s, w, l, Bhi, Blo, P, n0);
}

// ---------------- K3: edge kernel (R5-exact) ----------------
constexpr int MS = 72;
__global__ __launch_bounds__(256, 3) void k_edge(
        const int* __restrict__ eidx, const float* __restrict__ ea,
        const float* __restrict__ amf, const __hip_bfloat16* __restrict__ P,
        const float* __restrict__ Wm1_l, const float* __restrict__ bm1_l,
        const __hip_bfloat16* __restrict__ W2hi, const __hip_bfloat16* __restrict__ W2lo,
        const float* __restrict__ bm2_l, float* __restrict__ agg) {
    __shared__ __align__(16) __hip_bfloat16 m_s[128 * MS];
    __shared__ float ea_s[128][9];
    __shared__ float amf_s[128];
    __shared__ int src_s[128], dst_s[128];
    __shared__ float bm1_s[64], bm2_s[64];
    int tid = threadIdx.x;
    int l = tid & 63, w = tid >> 6;
    int e0 = blockIdx.x * 128;
    for (int idx = tid; idx < 128; idx += 256) {
        src_s[idx] = eidx[e0 + idx];
        dst_s[idx] = eidx[E + e0 + idx];
        amf_s[idx] = amf[e0 + idx];
    }
    for (int idx = tid; idx < 1024; idx += 256) ea_s[idx >> 3][idx & 7] = ea[(size_t)e0 * 8 + idx];
    if (tid < 64) { bm1_s[tid] = bm1_l[tid]; bm2_s[tid] = bm2_l[tid]; }
    float w130R[8];
#pragma unroll
    for (int j = 0; j < 8; ++j) w130R[j] = Wm1_l[130 * 512 + j * 64 + l];
    __syncthreads();

    // phase 1: m = bf16(silu(m1)), 2 vector loads per edge (R5 simple loop)
    float bm1k = bm1_s[l];
#pragma unroll 4
    for (int q = 0; q < 32; ++q) {
        int le = w * 32 + q;
        bf16x8 p1 = *(const bf16x8*)(P + (size_t)dst_s[le] * 1024 + l * 8);
        bf16x8 p2 = *(const bf16x8*)(P + (size_t)src_s[le] * 1024 + 512 + l * 8);
        float amfe = amf_s[le];
        float macc = bm1k;
#pragma unroll
        for (int j = 0; j < 8; ++j) {
            union { short s; __hip_bfloat16 b; } u1c, u2c;
            u1c.s = p1[j]; u2c.s = p2[j];
            float s = __bfloat162float(u1c.b) + __bfloat162float(u2c.b) + amfe * w130R[j];
            macc = fmaf(ea_s[le][j], s, macc);
        }
        m_s[le * MS + l] = __float2bfloat16(silu_f(macc));
    }
    __syncthreads();

    // phase 2: z-GEMM
    int c16 = l & 15, q = l >> 4;
    int e0w = w * 32;
    float eaA[2][8];
#pragma unroll
    for (int mt = 0; mt < 2; ++mt)
#pragma unroll
        for (int j = 0; j < 8; ++j) eaA[mt][j] = ea_s[e0w + mt * 16 + c16][j];

    f32x4 acc[2][4];
    f32x4 zero4 = {0.f, 0.f, 0.f, 0.f};
#pragma unroll
    for (int mt = 0; mt < 2; ++mt)
#pragma unroll
        for (int nt = 0; nt < 4; ++nt) acc[mt][nt] = zero4;

    int lofs = (c16 * 4 + q) * 8;
#pragma unroll 2
    for (int kk = 0; kk < 16; ++kk) {
        bf16x8 bh[4], bl[4];
#pragma unroll
        for (int nt = 0; nt < 4; ++nt) {
            int off = (kk * 4 + nt) * 512 + lofs;
            bh[nt] = *(const bf16x8*)(W2hi + off);
            bl[nt] = *(const bf16x8*)(W2lo + off);
        }
#pragma unroll
        for (int mt = 0; mt < 2; ++mt) {
            float mv = __bfloat162float(m_s[(e0w + mt * 16 + c16) * MS + kk * 4 + q]);
            union { bf16x8 v; __hip_bfloat16 h[8]; } au;
#pragma unroll
            for (int j = 0; j < 8; ++j) au.h[j] = __float2bfloat16(mv * eaA[mt][j]);
#pragma unroll
            for (int nt = 0; nt < 4; ++nt) {
                acc[mt][nt] = __builtin_amdgcn_mfma_f32_16x16x32_bf16(au.v, bh[nt], acc[mt][nt], 0, 0, 0);
                acc[mt][nt] = __builtin_amdgcn_mfma_f32_16x16x32_bf16(au.v, bl[nt], acc[mt][nt], 0, 0, 0);
            }
        }
    }
#pragma unroll
    for (int mt = 0; mt < 2; ++mt)
#pragma unroll
        for (int nt = 0; nt < 4; ++nt) {
            int kd = nt * 16 + c16;
            float bias = bm2_s[kd];
#pragma unroll
            for (int r = 0; r < 4; ++r) {
                int e = e0w + mt * 16 + q * 4 + r;
                float v = silu_f(bias + acc[mt][nt][r]);
                atomicAdd(&agg[(size_t)dst_s[e] * 64 + kd], v);
            }
        }
}

// ---------------- K4: fused node update (layer l) + P(layer l+1) + agg zero ----------------
__global__ __launch_bounds__(256) void k_upd_pre(
        const float* __restrict__ h_in, const float* __restrict__ anf,
        const float* __restrict__ na, const float* __restrict__ agg_in,
        const __hip_bfloat16* __restrict__ W1hi, const __hip_bfloat16* __restrict__ W1lo,
        const float* __restrict__ bu1_l,
        const __hip_bfloat16* __restrict__ W2hi_, const __hip_bfloat16* __restrict__ W2lo_,
        const float* __restrict__ bu2_l,
        const __hip_bfloat16* __restrict__ Bhi, const __hip_bfloat16* __restrict__ Blo,
        float* __restrict__ h, __hip_bfloat16* __restrict__ P, float* __restrict__ agg) {
    __shared__ __align__(16) __hip_bfloat16 xa_s[16 * 136];
    __shared__ __align__(16) __hip_bfloat16 u1_s[16 * 72];
    __shared__ float part_s[4][16][64];
    __shared__ __align__(16) __hip_bfloat16 ha_s[16 * 96];
    int tid = threadIdx.x;
    int w = tid >> 6, l = tid & 63;
    int n0 = blockIdx.x * 16;
    for (int idx = tid; idx < 16 * 132; idx += 256) {
        int r = idx / 132, c = idx % 132;
        int n = n0 + r;
        float v;
        if (c < 64) v = h_in[(size_t)n * 64 + c];
        else if (c == 64) v = anf[n];
        else if (c < 129) v = agg_in[(size_t)n * 64 + (c - 65)];
        else v = 0.f;
        xa_s[r * 136 + c] = __float2bfloat16(v);
    }
    int c16 = l & 15, q = l >> 4;
    float naA[8];
#pragma unroll
    for (int j = 0; j < 8; ++j) naA[j] = na[(size_t)(n0 + c16) * 8 + j];
    __syncthreads();
    // agg reads done -> zero this block's slice for next layer's edge pass
    float4 z4 = {0.f, 0.f, 0.f, 0.f};
    ((float4*)(agg + (size_t)blockIdx.x * 1024))[tid] = z4;
    int lofs = (c16 * 4 + q) * 8;
    zgemm_stage(xa_s, 136, 33, w, c16, q, lofs, naA, W1hi, W1lo, part_s);
    __syncthreads();
    for (int t = tid; t < 1024; t += 256) {
        int row = t >> 6, col = t & 63;
        float v = part_s[0][row][col] + part_s[1][row][col] + part_s[2][row][col] +
                  part_s[3][row][col] + bu1_l[col];
        u1_s[row * 72 + col] = __float2bfloat16(silu_f(v));
    }
    __syncthreads();
    zgemm_stage(u1_s, 72, 16, w, c16, q, lofs, naA, W2hi_, W2lo_, part_s);
    __syncthreads();
    for (int t = tid; t < 1024; t += 256) {
        int row = t >> 6, col = t & 63;
        float v = part_s[0][row][col] + part_s[1][row][col] + part_s[2][row][col] +
                  part_s[3][row][col] + bu2_l[col];
        float hn = h[(size_t)(n0 + row) * 64 + col] + v;
        h[(size_t)(n0 + row) * 64 + col] = hn;
        ha_s[row * 96 + col] = __float2bfloat16(hn);
    }
    if (tid < 16) ha_s[tid * 96 + 64] = __float2bfloat16(anf[n0 + tid]);
    for (int idx = tid; idx < 16 * 31; idx += 256) {
        int r = idx / 31, c = 65 + idx % 31;
        ha_s[r * 96 + c] = __float2bfloat16(0.f);
    }
    __syncthreads();
    pre_gemm_body(ha_s, w, l, Bhi, Blo, P, n0);
}

// ---------------- K6: fused node update (layer 1) + prepool -> p2 ----------------
__global__ __launch_bounds__(256) void k_upd_prepool(
        const float* __restrict__ h_in, const float* __restrict__ anf,
        const float* __restrict__ na, const float* __restrict__ agg_in,
        const __hip_bfloat16* __restrict__ W1hi, const __hip_bfloat16* __restrict__ W1lo,
        const float* __restrict__ bu1_l,
        const __hip_bfloat16* __restrict__ W2hi_, const __hip_bfloat16* __restrict__ W2lo_,
        const float* __restrict__ bu2_l,
        const __hip_bfloat16* __restrict__ Wp1hi, const __hip_bfloat16* __restrict__ Wp1lo,
        const float* __restrict__ bp1,
        const __hip_bfloat16* __restrict__ Wp2hi, const __hip_bfloat16* __restrict__ Wp2lo,
        const float* __restrict__ bp2,
        float* __restrict__ p2) {
    __shared__ __align__(16) __hip_bfloat16 xa_s[16 * 136];
    __shared__ __align__(16) __hip_bfloat16 u1_s[16 * 72];
    __shared__ __align__(16) __hip_bfloat16 x2_s[16 * 72];
    __shared__ float part_s[4][16][64];
    int tid = threadIdx.x;
    int w = tid >> 6, l = tid & 63;
    int n0 = blockIdx.x * 16;
    for (int idx = tid; idx < 16 * 132; idx += 256) {
        int r = idx / 132, c = idx % 132;
        int n = n0 + r;
        float v;
        if (c < 64) v = h_in[(size_t)n * 64 + c];
        else if (c == 64) v = anf[n];
        else if (c < 129) v = agg_in[(size_t)n * 64 + (c - 65)];
        else v = 0.f;
        xa_s[r * 136 + c] = __float2bfloat16(v);
    }
    int c16 = l & 15, q = l >> 4;
    float naA[8];
#pragma unroll
    for (int j = 0; j < 8; ++j) naA[j] = na[(size_t)(n0 + c16) * 8 + j];
    __syncthreads();
    int lofs = (c16 * 4 + q) * 8;
    // update layer 1
    zgemm_stage(xa_s, 136, 33, w, c16, q, lofs, naA, W1hi, W1lo, part_s);
    __syncthreads();
    for (int t = tid; t < 1024; t += 256) {
        int row = t >> 6, col = t & 63;
        float v = part_s[0][row][col] + part_s[1][row][col] + part_s[2][row][col] +
                  part_s[3][row][col] + bu1_l[col];
        u1_s[row * 72 + col] = __float2bfloat16(silu_f(v));
    }
    __syncthreads();
    zgemm_stage(u1_s, 72, 16, w, c16, q, lofs, naA, W2hi_, W2lo_, part_s);
    __syncthreads();
    for (int t = tid; t < 1024; t += 256) {
        int row = t >> 6, col = t & 63;
        float v = part_s[0][row][col] + part_s[1][row][col] + part_s[2][row][col] +
                  part_s[3][row][col] + bu2_l[col];
        float hn = h_in[(size_t)(n0 + row) * 64 + col] + v;   // h not needed after this kernel
        x2_s[row * 72 + col] = __float2bfloat16(hn);
    }
    __syncthreads();
    // prepool
    zgemm_stage(x2_s, 72, 16, w, c16, q, lofs, naA, Wp1hi, Wp1lo, part_s);
    __syncthreads();
    for (int t = tid; t < 1024; t += 256) {
        int row = t >> 6, col = t & 63;
        float v = part_s[0][row][col] + part_s[1][row][col] + part_s[2][row][col] +
                  part_s[3][row][col] + bp1[col];
        u1_s[row * 72 + col] = __float2bfloat16(silu_f(v));
    }
    __syncthreads();
    zgemm_stage(u1_s, 72, 16, w, c16, q, lofs, naA, Wp2hi, Wp2lo, part_s);
    __syncthreads();
    for (int t = tid; t < 1024; t += 256) {
        int row = t >> 6, col = t & 63;
        float v = part_s[0][row][col] + part_s[1][row][col] + part_s[2][row][col] +
                  part_s[3][row][col] + bp2[col];
        p2[(size_t)(n0 + row) * 64 + col] = v;
    }
}

// ---------------- K_pool: per-chunk segmented pooling (R5) ----------------
__global__ __launch_bounds__(256) void k_pool(
        const float* __restrict__ p2, const int* __restrict__ batch,
        float* __restrict__ partial_p, float* __restrict__ partial_cnt) {
    __shared__ float acc_s[16 * 64];
    __shared__ float cnt_s[16];
    int tid = threadIdx.x;
    for (int idx = tid; idx < 1024; idx += 256) acc_s[idx] = 0.f;
    if (tid < 16) cnt_s[tid] = 0.f;
    __syncthreads();
    int w = tid >> 6, k = tid & 63;
    int base = blockIdx.x * 125;
    for (int i = 0; i < 32; ++i) {
        int nl = i * 4 + w;
        if (nl < 125) {
            int n = base + nl;
            int b = batch[n];
            atomicAdd(&acc_s[b * 64 + k], p2[(size_t)n * 64 + k]);
            if (k == 0) atomicAdd(&cnt_s[b], 1.0f);
        }
    }
    __syncthreads();
    for (int idx = tid; idx < 1024; idx += 256)
        partial_p[(size_t)blockIdx.x * 1024 + idx] = acc_s[idx];
    if (tid < 16) partial_cnt[blockIdx.x * 16 + tid] = cnt_s[tid];
}

// ---------------- K7: reduce partials, mean, final MLP (R5) ----------------
__global__ __launch_bounds__(1024) void k_final(
        const float* __restrict__ partial_p, const float* __restrict__ partial_cnt,
        const float* __restrict__ Wq1, const float* __restrict__ bq1,
        const float* __restrict__ Wq2, const float* __restrict__ bq2,
        float* __restrict__ out) {
    __shared__ float g[16][64];
    int b = threadIdx.x >> 6, k = threadIdx.x & 63;
    float s = 0.f, cc = 0.f;
    for (int c = 0; c < POOL_CHUNKS; ++c) s += partial_p[(size_t)c * 1024 + b * 64 + k];
    for (int c = 0; c < POOL_CHUNKS; ++c) cc += partial_cnt[c * 16 + b];
    g[b][k] = s / fmaxf(cc, 1.0f);
    __syncthreads();
    float acc = bq1[k];
#pragma unroll
    for (int i = 0; i < 64; ++i) acc = fmaf(g[b][i], Wq1[i * 64 + k], acc);
    float v = silu_f(acc) * Wq2[k];
#pragma unroll
    for (int off = 32; off > 0; off >>= 1) v += __shfl_down(v, off, 64);
    if (k == 0) out[b] = v + bq2[0];
}

extern "C" void kernel_launch(void* const* d_in, const int* in_sizes, int n_in,
                              void* d_out, int out_size, void* d_ws, size_t ws_size,
                              hipStream_t stream) {
    const float* x    = (const float*)d_in[0];
    const int*   eidx = (const int*)  d_in[1];
    const float* ea   = (const float*)d_in[2];
    const float* na   = (const float*)d_in[3];
    const float* amf  = (const float*)d_in[4];
    const float* anf  = (const float*)d_in[5];
    const int*   batch= (const int*)  d_in[6];
    const float* W_emb= (const float*)d_in[7];
    const float* b_emb= (const float*)d_in[8];
    const float* Wm1  = (const float*)d_in[9];
    const float* bm1  = (const float*)d_in[10];
    const float* Wm2  = (const float*)d_in[11];
    const float* bm2  = (const float*)d_in[12];
    const float* Wu1  = (const float*)d_in[13];
    const float* bu1  = (const float*)d_in[14];
    const float* Wu2  = (const float*)d_in[15];
    const float* bu2  = (const float*)d_in[16];
    const float* Wp1  = (const float*)d_in[17];
    const float* bp1  = (const float*)d_in[18];
    const float* Wp2  = (const float*)d_in[19];
    const float* bp2  = (const float*)d_in[20];
    const float* Wq1  = (const float*)d_in[21];
    const float* bq1  = (const float*)d_in[22];
    const float* Wq2  = (const float*)d_in[23];
    const float* bq2  = (const float*)d_in[24];

    float* ws = (float*)d_ws;
    float* h      = ws;                            // N*64
    float* agg    = h + (size_t)N * 64;            // N*64
    float* p2     = agg + (size_t)N * 64;          // N*64
    float* part_p = p2 + (size_t)N * 64;           // 80*1024
    float* part_c = part_p + POOL_CHUNKS * 1024;   // 80*16
    float* fend   = part_c + POOL_CHUNKS * 16;
    __hip_bfloat16* Pb     = (__hip_bfloat16*)fend;          // N*1024
    __hip_bfloat16* W2hi   = Pb + (size_t)N * 1024;
    __hip_bfloat16* W2lo   = W2hi + 65536;
    __hip_bfloat16* Wu2hi  = W2lo + 65536;
    __hip_bfloat16* Wu2lo  = Wu2hi + 65536;
    __hip_bfloat16* Wp1hi  = Wu2lo + 65536;
    __hip_bfloat16* Wp1lo  = Wp1hi + 32768;
    __hip_bfloat16* Wp2hi  = Wp1lo + 32768;
    __hip_bfloat16* Wp2lo  = Wp2hi + 32768;
    __hip_bfloat16* Wu1hi  = Wp2lo + 32768;
    __hip_bfloat16* Wu1lo  = Wu1hi + 135168;
    __hip_bfloat16* Wm1phi = Wu1lo + 135168;
    __hip_bfloat16* Wm1plo = Wm1phi + 196608;

    k_w2<<<256, 256, 0, stream>>>(Wm2, W2hi, W2lo);
    k_w2<<<256, 256, 0, stream>>>(Wu2, Wu2hi, Wu2lo);
    k_w2<<<128, 256, 0, stream>>>(Wp1, Wp1hi, Wp1lo);
    k_w2<<<128, 256, 0, stream>>>(Wp2, Wp2hi, Wp2lo);
    k_wu1<<<528, 256, 0, stream>>>(Wu1, Wu1hi, Wu1lo);
    k_wm1p<<<768, 256, 0, stream>>>(Wm1, Wm1phi, Wm1plo);

    k_embed_pre<<<625, 256, 0, stream>>>(x, anf, na, W_emb, b_emb,
                                         Wm1phi, Wm1plo, h, Pb, agg);
    k_edge<<<E / 128, 256, 0, stream>>>(eidx, ea, amf, Pb,
                                        Wm1, bm1,
                                        W2hi, W2lo, bm2, agg);
    k_upd_pre<<<625, 256, 0, stream>>>(h, anf, na, agg,
                                       Wu1hi, Wu1lo, bu1,
                                       Wu2hi, Wu2lo, bu2,
                                       Wm1phi + 98304, Wm1plo + 98304,
                                       h, Pb, agg);
    k_edge<<<E / 128, 256, 0, stream>>>(eidx, ea, amf, Pb,
                                        Wm1 + (size_t)131 * 512, bm1 + 64,
                                        W2hi + 32768, W2lo + 32768, bm2 + 64, agg);
    k_upd_prepool<<<625, 256, 0, stream>>>(h, anf, na, agg,
                                           Wu1hi + 67584, Wu1lo + 67584, bu1 + 64,
                                           Wu2hi + 32768, Wu2lo + 32768, bu2 + 64,
                                           Wp1hi, Wp1lo, bp1, Wp2hi, Wp2lo, bp2, p2);
    k_pool<<<POOL_CHUNKS, 256, 0, stream>>>(p2, batch, part_p, part_c);
    k_final<<<1, 1024, 0, stream>>>(part_p, part_c, Wq1, bq1, Wq2, bq2, (float*)d_out);
}

// Round 10
// 420.677 us; speedup vs baseline: 1.4359x; 1.0355x over previous
//
#include <hip/hip_runtime.h>
#include <hip/hip_bf16.h>
#include <math.h>

// Problem constants
constexpr int N = 10000;
constexpr int E = 160000;
constexpr int B = 16;
constexpr int POOL_CHUNKS = 80;   // 80 * 125 = 10000

typedef short bf16x8 __attribute__((ext_vector_type(8)));
typedef float f32x4 __attribute__((ext_vector_type(4)));

__device__ __forceinline__ float silu_f(float x) {
    return x / (1.0f + __expf(-x));
}

// ---------------- weight reorders ----------------
__global__ __launch_bounds__(256) void k_w2(
        const float* __restrict__ Wsrc,
        __hip_bfloat16* __restrict__ Whi, __hip_bfloat16* __restrict__ Wlo) {
    int idx = blockIdx.x * 256 + threadIdx.x;
    int l = idx >> 15;
    int rem = idx & 32767;
    int kk = rem >> 11;
    int nt = (rem >> 9) & 3;
    int c  = (rem >> 5) & 15;
    int q  = (rem >> 3) & 3;
    int j  = rem & 7;
    int i = kk * 4 + q;
    int k = nt * 16 + c;
    float wv = Wsrc[(size_t)l * 32768 + i * 512 + j * 64 + k];
    __hip_bfloat16 hi = __float2bfloat16(wv);
    Whi[idx] = hi;
    Wlo[idx] = __float2bfloat16(wv - __bfloat162float(hi));
}

__global__ __launch_bounds__(256) void k_wu1(
        const float* __restrict__ Wu1,
        __hip_bfloat16* __restrict__ Whi, __hip_bfloat16* __restrict__ Wlo) {
    int idx = blockIdx.x * 256 + threadIdx.x;    // 2 * 67584
    int l = idx / 67584;
    int rem = idx % 67584;
    int kk = rem / 2048;          // 0..32
    int r2 = rem % 2048;
    int nt = (r2 >> 9) & 3;
    int c  = (r2 >> 5) & 15;
    int q  = (r2 >> 3) & 3;
    int j  = r2 & 7;
    int i = kk * 4 + q;           // 0..131
    float wv = (i < 129) ? Wu1[(size_t)l * 129 * 512 + i * 512 + j * 64 + nt * 16 + c] : 0.f;
    __hip_bfloat16 hi = __float2bfloat16(wv);
    Whi[idx] = hi;
    Wlo[idx] = __float2bfloat16(wv - __bfloat162float(hi));
}

// m1 z-form B (bf16 hi only): 35 K-chunks; i' map: 0..64 dst, 68..132 src(+65), 136 amf
__global__ __launch_bounds__(256) void k_wm1z(
        const float* __restrict__ Wm1, __hip_bfloat16* __restrict__ Whi) {
    int idx = blockIdx.x * 256 + threadIdx.x;   // 2 * 71680 = 143360
    int l = idx / 71680;
    int rem = idx % 71680;
    int kkn = rem >> 9;          // 0..139 = kk*4+nt
    int off = rem & 511;
    int kk = kkn >> 2;
    int c16 = off >> 5;
    int q = (off >> 3) & 3;
    int j = off & 7;
    int ip = kk * 4 + q;
    int k = (kkn & 3) * 16 + c16;
    float wv = 0.f;
    int wi = -1;
    if (kk < 17) { if (ip <= 64) wi = ip; }
    else if (kk < 34) { int s = ip - 68; if (s >= 0 && s <= 64) wi = 65 + s; }
    else { if (q == 0) wi = 130; }
    if (wi >= 0) wv = Wm1[((size_t)l * 131 + wi) * 512 + j * 64 + k];
    Whi[idx] = __float2bfloat16(wv);
}

// ---------------- device helper: one z-GEMM stage, 4 waves split K, result into part_s ----------------
__device__ __forceinline__ void zgemm_stage(
        const __hip_bfloat16* xsrc, int xstride, int kkmax, int w, int c16, int q, int lofs,
        const float* naA,
        const __hip_bfloat16* __restrict__ Whi, const __hip_bfloat16* __restrict__ Wlo,
        float (*part_s)[16][64]) {
    f32x4 zero4 = {0.f, 0.f, 0.f, 0.f};
    f32x4 acc[4];
#pragma unroll
    for (int nt = 0; nt < 4; ++nt) acc[nt] = zero4;
    for (int kk = w; kk < kkmax; kk += 4) {
        bf16x8 bh[4], bl[4];
#pragma unroll
        for (int nt = 0; nt < 4; ++nt) {
            int off = (kk * 4 + nt) * 512 + lofs;
            bh[nt] = *(const bf16x8*)(Whi + off);
            bl[nt] = *(const bf16x8*)(Wlo + off);
        }
        float mv = __bfloat162float(xsrc[c16 * xstride + kk * 4 + q]);
        union { bf16x8 v; __hip_bfloat16 hx[8]; } au;
#pragma unroll
        for (int j = 0; j < 8; ++j) au.hx[j] = __float2bfloat16(mv * naA[j]);
#pragma unroll
        for (int nt = 0; nt < 4; ++nt) {
            acc[nt] = __builtin_amdgcn_mfma_f32_16x16x32_bf16(au.v, bh[nt], acc[nt], 0, 0, 0);
            acc[nt] = __builtin_amdgcn_mfma_f32_16x16x32_bf16(au.v, bl[nt], acc[nt], 0, 0, 0);
        }
    }
#pragma unroll
    for (int nt = 0; nt < 4; ++nt)
#pragma unroll
        for (int r = 0; r < 4; ++r) part_s[w][q * 4 + r][nt * 16 + c16] = acc[nt][r];
}

// ---------------- K1: embed -> h fp32 + hb bf16 + agg zero ----------------
__global__ __launch_bounds__(256) void k_embed_hb(
        const float* __restrict__ x, const float* __restrict__ anf,
        const float* __restrict__ na, const float* __restrict__ W_emb,
        const float* __restrict__ b_emb,
        float* __restrict__ h, __hip_bfloat16* __restrict__ hb, float* __restrict__ agg) {
    __shared__ float xs[16][18];
    __shared__ float na_s[16][8];
    int tid = threadIdx.x, w = tid >> 6, l = tid & 63;
    int n0 = blockIdx.x * 16;
    {
        int r = tid >> 4, c = tid & 15;
        xs[r][c] = x[(size_t)(n0 + r) * 16 + c];
    }
    if (tid < 16) xs[tid][16] = anf[n0 + tid];
    if (tid < 128) na_s[tid >> 3][tid & 7] = na[(size_t)n0 * 8 + tid];
    float4 z4 = {0.f, 0.f, 0.f, 0.f};
    ((float4*)(agg + (size_t)blockIdx.x * 1024))[tid] = z4;
    __syncthreads();
    float acc[4];
#pragma unroll
    for (int t = 0; t < 4; ++t) acc[t] = b_emb[l];
    for (int i = 0; i < 17; ++i) {
#pragma unroll
        for (int j = 0; j < 8; ++j) {
            float wv = W_emb[(i * 8 + j) * 64 + l];
#pragma unroll
            for (int t = 0; t < 4; ++t) {
                int nn = w * 4 + t;
                acc[t] = fmaf(xs[nn][i] * na_s[nn][j], wv, acc[t]);
            }
        }
    }
#pragma unroll
    for (int t = 0; t < 4; ++t) {
        int n = n0 + w * 4 + t;
        h[(size_t)n * 64 + l] = acc[t];
        hb[(size_t)n * 72 + l] = __float2bfloat16(acc[t]);
    }
    if (tid < 16) hb[(size_t)(n0 + tid) * 72 + 64] = __float2bfloat16(xs[tid][16]);
    for (int idx = tid; idx < 16 * 7; idx += 256) {
        int r = idx / 7, c = 65 + idx % 7;
        hb[(size_t)(n0 + r) * 72 + c] = __float2bfloat16(0.f);
    }
}

// ---------------- K3: edge kernel — direct m1 z-GEMM from hb (no P) ----------------
constexpr int MS = 72;
__global__ __launch_bounds__(256, 3) void k_edge(
        const int* __restrict__ eidx, const float* __restrict__ ea,
        const float* __restrict__ amf, const __hip_bfloat16* __restrict__ hb,
        const __hip_bfloat16* __restrict__ W1hi, const float* __restrict__ bm1_l,
        const __hip_bfloat16* __restrict__ W2hi, const __hip_bfloat16* __restrict__ W2lo,
        const float* __restrict__ bm2_l, float* __restrict__ agg) {
    __shared__ __align__(16) __hip_bfloat16 xaD_s[128 * MS];   // aliased as m_s after m1
    __shared__ __align__(16) __hip_bfloat16 xaS_s[128 * MS];
    __shared__ float ea_s[128][9];
    __shared__ float amf_s[128];
    __shared__ int src_s[128], dst_s[128];
    __shared__ float bm1_s[64], bm2_s[64];
    int tid = threadIdx.x;
    int l = tid & 63, w = tid >> 6;
    int e0 = blockIdx.x * 128;
    for (int idx = tid; idx < 128; idx += 256) {
        src_s[idx] = eidx[e0 + idx];
        dst_s[idx] = eidx[E + e0 + idx];
        amf_s[idx] = amf[e0 + idx];
    }
    for (int idx = tid; idx < 1024; idx += 256) ea_s[idx >> 3][idx & 7] = ea[(size_t)e0 * 8 + idx];
    if (tid < 64) { bm1_s[tid] = bm1_l[tid]; bm2_s[tid] = bm2_l[tid]; }
    __syncthreads();
    // gather h_aug rows (L2-resident hb table), 9 x 16B chunks per row
    for (int idx = tid; idx < 128 * 9; idx += 256) {
        int r = idx / 9, c = (idx % 9) * 8;
        *(float4*)&xaD_s[r * MS + c] = *(const float4*)(hb + (size_t)dst_s[r] * MS + c);
        *(float4*)&xaS_s[r * MS + c] = *(const float4*)(hb + (size_t)src_s[r] * MS + c);
    }
    __syncthreads();

    int c16 = l & 15, q = l >> 4;
    int e0w = w * 32;
    float eaA[2][8];
    float amfA[2];
#pragma unroll
    for (int mt = 0; mt < 2; ++mt) {
#pragma unroll
        for (int j = 0; j < 8; ++j) eaA[mt][j] = ea_s[e0w + mt * 16 + c16][j];
        amfA[mt] = amf_s[e0w + mt * 16 + c16];
    }
    int lofs = (c16 * 4 + q) * 8;
    f32x4 zero4 = {0.f, 0.f, 0.f, 0.f};

    // ---- phase 1: m1 z-GEMM, K = 35 chunks (17 dst + 17 src + 1 amf) ----
    f32x4 acc1[2][4];
#pragma unroll
    for (int mt = 0; mt < 2; ++mt)
#pragma unroll
        for (int nt = 0; nt < 4; ++nt) acc1[mt][nt] = zero4;
#pragma unroll 2
    for (int kk = 0; kk < 17; ++kk) {
        bf16x8 bh[4];
#pragma unroll
        for (int nt = 0; nt < 4; ++nt)
            bh[nt] = *(const bf16x8*)(W1hi + (kk * 4 + nt) * 512 + lofs);
#pragma unroll
        for (int mt = 0; mt < 2; ++mt) {
            float xv = __bfloat162float(xaD_s[(e0w + mt * 16 + c16) * MS + kk * 4 + q]);
            union { bf16x8 v; __hip_bfloat16 hx[8]; } au;
#pragma unroll
            for (int j = 0; j < 8; ++j) au.hx[j] = __float2bfloat16(xv * eaA[mt][j]);
#pragma unroll
            for (int nt = 0; nt < 4; ++nt)
                acc1[mt][nt] = __builtin_amdgcn_mfma_f32_16x16x32_bf16(au.v, bh[nt], acc1[mt][nt], 0, 0, 0);
        }
    }
#pragma unroll 2
    for (int kk = 17; kk < 34; ++kk) {
        bf16x8 bh[4];
#pragma unroll
        for (int nt = 0; nt < 4; ++nt)
            bh[nt] = *(const bf16x8*)(W1hi + (kk * 4 + nt) * 512 + lofs);
#pragma unroll
        for (int mt = 0; mt < 2; ++mt) {
            float xv = __bfloat162float(xaS_s[(e0w + mt * 16 + c16) * MS + kk * 4 + q - 68]);
            union { bf16x8 v; __hip_bfloat16 hx[8]; } au;
#pragma unroll
            for (int j = 0; j < 8; ++j) au.hx[j] = __float2bfloat16(xv * eaA[mt][j]);
#pragma unroll
            for (int nt = 0; nt < 4; ++nt)
                acc1[mt][nt] = __builtin_amdgcn_mfma_f32_16x16x32_bf16(au.v, bh[nt], acc1[mt][nt], 0, 0, 0);
        }
    }
    {   // kk = 34: amf chunk (q==0 rows only)
        bf16x8 bh[4];
#pragma unroll
        for (int nt = 0; nt < 4; ++nt)
            bh[nt] = *(const bf16x8*)(W1hi + (34 * 4 + nt) * 512 + lofs);
#pragma unroll
        for (int mt = 0; mt < 2; ++mt) {
            float xv = (q == 0) ? amfA[mt] : 0.f;
            union { bf16x8 v; __hip_bfloat16 hx[8]; } au;
#pragma unroll
            for (int j = 0; j < 8; ++j) au.hx[j] = __float2bfloat16(xv * eaA[mt][j]);
#pragma unroll
            for (int nt = 0; nt < 4; ++nt)
                acc1[mt][nt] = __builtin_amdgcn_mfma_f32_16x16x32_bf16(au.v, bh[nt], acc1[mt][nt], 0, 0, 0);
        }
    }
    // extract m = silu(bm1 + m1) into xaD_s (wave-private rows; DS pipe is in-order per wave)
#pragma unroll
    for (int mt = 0; mt < 2; ++mt)
#pragma unroll
        for (int nt = 0; nt < 4; ++nt) {
            int kd = nt * 16 + c16;
            float bias = bm1_s[kd];
#pragma unroll
            for (int r = 0; r < 4; ++r) {
                int e = e0w + mt * 16 + q * 4 + r;
                xaD_s[e * MS + kd] = __float2bfloat16(silu_f(bias + acc1[mt][nt][r]));
            }
        }

    // ---- phase 2: m2 z-GEMM (reads m from xaD_s, hi/lo weights) ----
    f32x4 acc[2][4];
#pragma unroll
    for (int mt = 0; mt < 2; ++mt)
#pragma unroll
        for (int nt = 0; nt < 4; ++nt) acc[mt][nt] = zero4;
#pragma unroll 2
    for (int kk = 0; kk < 16; ++kk) {
        bf16x8 bh[4], bl[4];
#pragma unroll
        for (int nt = 0; nt < 4; ++nt) {
            int off = (kk * 4 + nt) * 512 + lofs;
            bh[nt] = *(const bf16x8*)(W2hi + off);
            bl[nt] = *(const bf16x8*)(W2lo + off);
        }
#pragma unroll
        for (int mt = 0; mt < 2; ++mt) {
            float mv = __bfloat162float(xaD_s[(e0w + mt * 16 + c16) * MS + kk * 4 + q]);
            union { bf16x8 v; __hip_bfloat16 h[8]; } au;
#pragma unroll
            for (int j = 0; j < 8; ++j) au.h[j] = __float2bfloat16(mv * eaA[mt][j]);
#pragma unroll
            for (int nt = 0; nt < 4; ++nt) {
                acc[mt][nt] = __builtin_amdgcn_mfma_f32_16x16x32_bf16(au.v, bh[nt], acc[mt][nt], 0, 0, 0);
                acc[mt][nt] = __builtin_amdgcn_mfma_f32_16x16x32_bf16(au.v, bl[nt], acc[mt][nt], 0, 0, 0);
            }
        }
    }
#pragma unroll
    for (int mt = 0; mt < 2; ++mt)
#pragma unroll
        for (int nt = 0; nt < 4; ++nt) {
            int kd = nt * 16 + c16;
            float bias = bm2_s[kd];
#pragma unroll
            for (int r = 0; r < 4; ++r) {
                int e = e0w + mt * 16 + q * 4 + r;
                float v = silu_f(bias + acc[mt][nt][r]);
                atomicAdd(&agg[(size_t)dst_s[e] * 64 + kd], v);
            }
        }
}

// ---------------- K4: node update + write h/hb + agg zero ----------------
__global__ __launch_bounds__(256) void k_upd_hb(
        const float* __restrict__ h_in, const float* __restrict__ anf,
        const float* __restrict__ na, const float* __restrict__ agg_in,
        const __hip_bfloat16* __restrict__ W1hi, const __hip_bfloat16* __restrict__ W1lo,
        const float* __restrict__ bu1_l,
        const __hip_bfloat16* __restrict__ W2hi_, const __hip_bfloat16* __restrict__ W2lo_,
        const float* __restrict__ bu2_l,
        float* __restrict__ h, __hip_bfloat16* __restrict__ hb, float* __restrict__ agg) {
    __shared__ __align__(16) __hip_bfloat16 xa_s[16 * 136];
    __shared__ __align__(16) __hip_bfloat16 u1_s[16 * 72];
    __shared__ float part_s[4][16][64];
    int tid = threadIdx.x;
    int w = tid >> 6, l = tid & 63;
    int n0 = blockIdx.x * 16;
    for (int idx = tid; idx < 16 * 132; idx += 256) {
        int r = idx / 132, c = idx % 132;
        int n = n0 + r;
        float v;
        if (c < 64) v = h_in[(size_t)n * 64 + c];
        else if (c == 64) v = anf[n];
        else if (c < 129) v = agg_in[(size_t)n * 64 + (c - 65)];
        else v = 0.f;
        xa_s[r * 136 + c] = __float2bfloat16(v);
    }
    int c16 = l & 15, q = l >> 4;
    float naA[8];
#pragma unroll
    for (int j = 0; j < 8; ++j) naA[j] = na[(size_t)(n0 + c16) * 8 + j];
    __syncthreads();
    float4 z4 = {0.f, 0.f, 0.f, 0.f};
    ((float4*)(agg + (size_t)blockIdx.x * 1024))[tid] = z4;
    int lofs = (c16 * 4 + q) * 8;
    zgemm_stage(xa_s, 136, 33, w, c16, q, lofs, naA, W1hi, W1lo, part_s);
    __syncthreads();
    for (int t = tid; t < 1024; t += 256) {
        int row = t >> 6, col = t & 63;
        float v = part_s[0][row][col] + part_s[1][row][col] + part_s[2][row][col] +
                  part_s[3][row][col] + bu1_l[col];
        u1_s[row * 72 + col] = __float2bfloat16(silu_f(v));
    }
    __syncthreads();
    zgemm_stage(u1_s, 72, 16, w, c16, q, lofs, naA, W2hi_, W2lo_, part_s);
    __syncthreads();
    for (int t = tid; t < 1024; t += 256) {
        int row = t >> 6, col = t & 63;
        float v = part_s[0][row][col] + part_s[1][row][col] + part_s[2][row][col] +
                  part_s[3][row][col] + bu2_l[col];
        int n = n0 + row;
        float hn = h[(size_t)n * 64 + col] + v;
        h[(size_t)n * 64 + col] = hn;
        hb[(size_t)n * 72 + col] = __float2bfloat16(hn);
    }
    if (tid < 16) hb[(size_t)(n0 + tid) * 72 + 64] = __float2bfloat16(anf[n0 + tid]);
    for (int idx = tid; idx < 16 * 7; idx += 256) {
        int r = idx / 7, c = 65 + idx % 7;
        hb[(size_t)(n0 + r) * 72 + c] = __float2bfloat16(0.f);
    }
}

// ---------------- K6: fused node update (layer 1) + prepool -> p2 (R9) ----------------
__global__ __launch_bounds__(256) void k_upd_prepool(
        const float* __restrict__ h_in, const float* __restrict__ anf,
        const float* __restrict__ na, const float* __restrict__ agg_in,
        const __hip_bfloat16* __restrict__ W1hi, const __hip_bfloat16* __restrict__ W1lo,
        const float* __restrict__ bu1_l,
        const __hip_bfloat16* __restrict__ W2hi_, const __hip_bfloat16* __restrict__ W2lo_,
        const float* __restrict__ bu2_l,
        const __hip_bfloat16* __restrict__ Wp1hi, const __hip_bfloat16* __restrict__ Wp1lo,
        const float* __restrict__ bp1,
        const __hip_bfloat16* __restrict__ Wp2hi, const __hip_bfloat16* __restrict__ Wp2lo,
        const float* __restrict__ bp2,
        float* __restrict__ p2) {
    __shared__ __align__(16) __hip_bfloat16 xa_s[16 * 136];
    __shared__ __align__(16) __hip_bfloat16 u1_s[16 * 72];
    __shared__ __align__(16) __hip_bfloat16 x2_s[16 * 72];
    __shared__ float part_s[4][16][64];
    int tid = threadIdx.x;
    int w = tid >> 6, l = tid & 63;
    int n0 = blockIdx.x * 16;
    for (int idx = tid; idx < 16 * 132; idx += 256) {
        int r = idx / 132, c = idx % 132;
        int n = n0 + r;
        float v;
        if (c < 64) v = h_in[(size_t)n * 64 + c];
        else if (c == 64) v = anf[n];
        else if (c < 129) v = agg_in[(size_t)n * 64 + (c - 65)];
        else v = 0.f;
        xa_s[r * 136 + c] = __float2bfloat16(v);
    }
    int c16 = l & 15, q = l >> 4;
    float naA[8];
#pragma unroll
    for (int j = 0; j < 8; ++j) naA[j] = na[(size_t)(n0 + c16) * 8 + j];
    __syncthreads();
    int lofs = (c16 * 4 + q) * 8;
    zgemm_stage(xa_s, 136, 33, w, c16, q, lofs, naA, W1hi, W1lo, part_s);
    __syncthreads();
    for (int t = tid; t < 1024; t += 256) {
        int row = t >> 6, col = t & 63;
        float v = part_s[0][row][col] + part_s[1][row][col] + part_s[2][row][col] +
                  part_s[3][row][col] + bu1_l[col];
        u1_s[row * 72 + col] = __float2bfloat16(silu_f(v));
    }
    __syncthreads();
    zgemm_stage(u1_s, 72, 16, w, c16, q, lofs, naA, W2hi_, W2lo_, part_s);
    __syncthreads();
    for (int t = tid; t < 1024; t += 256) {
        int row = t >> 6, col = t & 63;
        float v = part_s[0][row][col] + part_s[1][row][col] + part_s[2][row][col] +
                  part_s[3][row][col] + bu2_l[col];
        float hn = h_in[(size_t)(n0 + row) * 64 + col] + v;
        x2_s[row * 72 + col] = __float2bfloat16(hn);
    }
    __syncthreads();
    zgemm_stage(x2_s, 72, 16, w, c16, q, lofs, naA, Wp1hi, Wp1lo, part_s);
    __syncthreads();
    for (int t = tid; t < 1024; t += 256) {
        int row = t >> 6, col = t & 63;
        float v = part_s[0][row][col] + part_s[1][row][col] + part_s[2][row][col] +
                  part_s[3][row][col] + bp1[col];
        u1_s[row * 72 + col] = __float2bfloat16(silu_f(v));
    }
    __syncthreads();
    zgemm_stage(u1_s, 72, 16, w, c16, q, lofs, naA, Wp2hi, Wp2lo, part_s);
    __syncthreads();
    for (int t = tid; t < 1024; t += 256) {
        int row = t >> 6, col = t & 63;
        float v = part_s[0][row][col] + part_s[1][row][col] + part_s[2][row][col] +
                  part_s[3][row][col] + bp2[col];
        p2[(size_t)(n0 + row) * 64 + col] = v;
    }
}

// ---------------- K_pool ----------------
__global__ __launch_bounds__(256) void k_pool(
        const float* __restrict__ p2, const int* __restrict__ batch,
        float* __restrict__ partial_p, float* __restrict__ partial_cnt) {
    __shared__ float acc_s[16 * 64];
    __shared__ float cnt_s[16];
    int tid = threadIdx.x;
    for (int idx = tid; idx < 1024; idx += 256) acc_s[idx] = 0.f;
    if (tid < 16) cnt_s[tid] = 0.f;
    __syncthreads();
    int w = tid >> 6, k = tid & 63;
    int base = blockIdx.x * 125;
    for (int i = 0; i < 32; ++i) {
        int nl = i * 4 + w;
        if (nl < 125) {
            int n = base + nl;
            int b = batch[n];
            atomicAdd(&acc_s[b * 64 + k], p2[(size_t)n * 64 + k]);
            if (k == 0) atomicAdd(&cnt_s[b], 1.0f);
        }
    }
    __syncthreads();
    for (int idx = tid; idx < 1024; idx += 256)
        partial_p[(size_t)blockIdx.x * 1024 + idx] = acc_s[idx];
    if (tid < 16) partial_cnt[blockIdx.x * 16 + tid] = cnt_s[tid];
}

// ---------------- K7: reduce partials, mean, final MLP ----------------
__global__ __launch_bounds__(1024) void k_final(
        const float* __restrict__ partial_p, const float* __restrict__ partial_cnt,
        const float* __restrict__ Wq1, const float* __restrict__ bq1,
        const float* __restrict__ Wq2, const float* __restrict__ bq2,
        float* __restrict__ out) {
    __shared__ float g[16][64];
    int b = threadIdx.x >> 6, k = threadIdx.x & 63;
    float s = 0.f, cc = 0.f;
    for (int c = 0; c < POOL_CHUNKS; ++c) s += partial_p[(size_t)c * 1024 + b * 64 + k];
    for (int c = 0; c < POOL_CHUNKS; ++c) cc += partial_cnt[c * 16 + b];
    g[b][k] = s / fmaxf(cc, 1.0f);
    __syncthreads();
    float acc = bq1[k];
#pragma unroll
    for (int i = 0; i < 64; ++i) acc = fmaf(g[b][i], Wq1[i * 64 + k], acc);
    float v = silu_f(acc) * Wq2[k];
#pragma unroll
    for (int off = 32; off > 0; off >>= 1) v += __shfl_down(v, off, 64);
    if (k == 0) out[b] = v + bq2[0];
}

extern "C" void kernel_launch(void* const* d_in, const int* in_sizes, int n_in,
                              void* d_out, int out_size, void* d_ws, size_t ws_size,
                              hipStream_t stream) {
    const float* x    = (const float*)d_in[0];
    const int*   eidx = (const int*)  d_in[1];
    const float* ea   = (const float*)d_in[2];
    const float* na   = (const float*)d_in[3];
    const float* amf  = (const float*)d_in[4];
    const float* anf  = (const float*)d_in[5];
    const int*   batch= (const int*)  d_in[6];
    const float* W_emb= (const float*)d_in[7];
    const float* b_emb= (const float*)d_in[8];
    const float* Wm1  = (const float*)d_in[9];
    const float* bm1  = (const float*)d_in[10];
    const float* Wm2  = (const float*)d_in[11];
    const float* bm2  = (const float*)d_in[12];
    const float* Wu1  = (const float*)d_in[13];
    const float* bu1  = (const float*)d_in[14];
    const float* Wu2  = (const float*)d_in[15];
    const float* bu2  = (const float*)d_in[16];
    const float* Wp1  = (const float*)d_in[17];
    const float* bp1  = (const float*)d_in[18];
    const float* Wp2  = (const float*)d_in[19];
    const float* bp2  = (const float*)d_in[20];
    const float* Wq1  = (const float*)d_in[21];
    const float* bq1  = (const float*)d_in[22];
    const float* Wq2  = (const float*)d_in[23];
    const float* bq2  = (const float*)d_in[24];

    float* ws = (float*)d_ws;
    float* h      = ws;                            // N*64
    float* agg    = h + (size_t)N * 64;            // N*64
    float* p2     = agg + (size_t)N * 64;          // N*64
    float* part_p = p2 + (size_t)N * 64;           // 80*1024
    float* part_c = part_p + POOL_CHUNKS * 1024;   // 80*16
    float* fend   = part_c + POOL_CHUNKS * 16;
    __hip_bfloat16* hb     = (__hip_bfloat16*)fend;          // N*72
    __hip_bfloat16* W2hi   = hb + (size_t)N * 72;
    __hip_bfloat16* W2lo   = W2hi + 65536;
    __hip_bfloat16* Wu2hi  = W2lo + 65536;
    __hip_bfloat16* Wu2lo  = Wu2hi + 65536;
    __hip_bfloat16* Wp1hi  = Wu2lo + 65536;
    __hip_bfloat16* Wp1lo  = Wp1hi + 32768;
    __hip_bfloat16* Wp2hi  = Wp1lo + 32768;
    __hip_bfloat16* Wp2lo  = Wp2hi + 32768;
    __hip_bfloat16* Wu1hi  = Wp2lo + 32768;
    __hip_bfloat16* Wu1lo  = Wu1hi + 135168;
    __hip_bfloat16* Wm1zhi = Wu1lo + 135168;       // 2*71680

    k_w2<<<256, 256, 0, stream>>>(Wm2, W2hi, W2lo);
    k_w2<<<256, 256, 0, stream>>>(Wu2, Wu2hi, Wu2lo);
    k_w2<<<128, 256, 0, stream>>>(Wp1, Wp1hi, Wp1lo);
    k_w2<<<128, 256, 0, stream>>>(Wp2, Wp2hi, Wp2lo);
    k_wu1<<<528, 256, 0, stream>>>(Wu1, Wu1hi, Wu1lo);
    k_wm1z<<<560, 256, 0, stream>>>(Wm1, Wm1zhi);

    k_embed_hb<<<625, 256, 0, stream>>>(x, anf, na, W_emb, b_emb, h, hb, agg);
    k_edge<<<E / 128, 256, 0, stream>>>(eidx, ea, amf, hb,
                                        Wm1zhi, bm1,
                                        W2hi, W2lo, bm2, agg);
    k_upd_hb<<<625, 256, 0, stream>>>(h, anf, na, agg,
                                      Wu1hi, Wu1lo, bu1,
                                      Wu2hi, Wu2lo, bu2,
                                      h, hb, agg);
    k_edge<<<E / 128, 256, 0, stream>>>(eidx, ea, amf, hb,
                                        Wm1zhi + 71680, bm1 + 64,
                                        W2hi + 32768, W2lo + 32768, bm2 + 64, agg);
    k_upd_prepool<<<625, 256, 0, stream>>>(h, anf, na, agg,
                                           Wu1hi + 67584, Wu1lo + 67584, bu1 + 64,
                                           Wu2hi + 32768, Wu2lo + 32768, bu2 + 64,
                                           Wp1hi, Wp1lo, bp1, Wp2hi, Wp2lo, bp2, p2);
    k_pool<<<POOL_CHUNKS, 256, 0, stream>>>(p2, batch, part_p, part_c);
    k_final<<<1, 1024, 0, stream>>>(part_p, part_c, Wq1, bq1, Wq2, bq2, (float*)d_out);
}

// Round 11
// 412.520 us; speedup vs baseline: 1.4643x; 1.0198x over previous
//
#include <hip/hip_runtime.h>
#include <hip/hip_bf16.h>
#include <math.h>

// Problem constants
constexpr int N = 10000;
constexpr int E = 160000;
constexpr int B = 16;
constexpr int POOL_CHUNKS = 80;   // 80 * 125 = 10000
constexpr int MS = 72;            // m_s row stride (bf16)
constexpr int HS = 96;            // hb row stride: 4 q-sections x 24 (17 used + pad)

typedef short bf16x8 __attribute__((ext_vector_type(8)));
typedef short bf16x4 __attribute__((ext_vector_type(4)));
typedef float f32x4 __attribute__((ext_vector_type(4)));

__device__ __forceinline__ float silu_f(float x) {
    return x / (1.0f + __expf(-x));
}
__device__ __forceinline__ float bf2f(short s) {
    union { unsigned u; float f; } c; c.u = (unsigned)(unsigned short)s << 16; return c.f;
}

// ---------------- weight reorders (q-major i-mapping: i = q*L + kk) ----------------
// z-B for 64-wide inputs: i = q*16 + kk
__global__ __launch_bounds__(256) void k_w2(
        const float* __restrict__ Wsrc,
        __hip_bfloat16* __restrict__ Whi, __hip_bfloat16* __restrict__ Wlo) {
    int idx = blockIdx.x * 256 + threadIdx.x;
    int l = idx >> 15;
    int rem = idx & 32767;
    int kk = rem >> 11;
    int nt = (rem >> 9) & 3;
    int c  = (rem >> 5) & 15;
    int q  = (rem >> 3) & 3;
    int j  = rem & 7;
    int i = q * 16 + kk;
    int k = nt * 16 + c;
    float wv = Wsrc[(size_t)l * 32768 + i * 512 + j * 64 + k];
    __hip_bfloat16 hi = __float2bfloat16(wv);
    Whi[idx] = hi;
    Wlo[idx] = __float2bfloat16(wv - __bfloat162float(hi));
}

// z-B for update stage1 (K=132, real 129): i = q*33 + kk
__global__ __launch_bounds__(256) void k_wu1(
        const float* __restrict__ Wu1,
        __hip_bfloat16* __restrict__ Whi, __hip_bfloat16* __restrict__ Wlo) {
    int idx = blockIdx.x * 256 + threadIdx.x;    // 2 * 67584
    int l = idx / 67584;
    int rem = idx % 67584;
    int kk = rem / 2048;          // 0..32
    int r2 = rem % 2048;
    int nt = (r2 >> 9) & 3;
    int c  = (r2 >> 5) & 15;
    int q  = (r2 >> 3) & 3;
    int j  = r2 & 7;
    int i = q * 33 + kk;          // 0..131
    float wv = (i < 129) ? Wu1[(size_t)l * 129 * 512 + i * 512 + j * 64 + nt * 16 + c] : 0.f;
    __hip_bfloat16 hi = __float2bfloat16(wv);
    Whi[idx] = hi;
    Wlo[idx] = __float2bfloat16(wv - __bfloat162float(hi));
}

// m1 z-B (bf16 hi only), 35 chunks: kk<17 dst (i=q*17+kk), kk<34 src, kk=34 amf(q==0)
__global__ __launch_bounds__(256) void k_wm1z(
        const float* __restrict__ Wm1, __hip_bfloat16* __restrict__ Whi) {
    int idx = blockIdx.x * 256 + threadIdx.x;   // 2 * 71680
    int l = idx / 71680;
    int rem = idx % 71680;
    int kkn = rem >> 9;          // 0..139
    int off = rem & 511;
    int kk = kkn >> 2;
    int nt = kkn & 3;
    int c16 = off >> 5;
    int q = (off >> 3) & 3;
    int j = off & 7;
    int k = nt * 16 + c16;
    int wi = -1;
    if (kk < 17) { int i = q * 17 + kk; if (i <= 64) wi = i; }
    else if (kk < 34) { int s = q * 17 + (kk - 17); if (s <= 64) wi = 65 + s; }
    else { if (q == 0) wi = 130; }
    float wv = (wi >= 0) ? Wm1[((size_t)l * 131 + wi) * 512 + j * 64 + k] : 0.f;
    Whi[idx] = __float2bfloat16(wv);
}

// ---------------- device helper: one z-GEMM stage, 4 waves split K, q-major x index ----------------
__device__ __forceinline__ void zgemm_stage(
        const __hip_bfloat16* xsrc, int xstride, int kkmax, int Lq,
        int w, int c16, int q, int lofs, const float* naA,
        const __hip_bfloat16* __restrict__ Whi, const __hip_bfloat16* __restrict__ Wlo,
        float (*part_s)[16][64]) {
    f32x4 zero4 = {0.f, 0.f, 0.f, 0.f};
    f32x4 acc[4];
#pragma unroll
    for (int nt = 0; nt < 4; ++nt) acc[nt] = zero4;
    for (int kk = w; kk < kkmax; kk += 4) {
        bf16x8 bh[4], bl[4];
#pragma unroll
        for (int nt = 0; nt < 4; ++nt) {
            int off = (kk * 4 + nt) * 512 + lofs;
            bh[nt] = *(const bf16x8*)(Whi + off);
            bl[nt] = *(const bf16x8*)(Wlo + off);
        }
        float mv = __bfloat162float(xsrc[c16 * xstride + q * Lq + kk]);
        union { bf16x8 v; __hip_bfloat16 hx[8]; } au;
#pragma unroll
        for (int j = 0; j < 8; ++j) au.hx[j] = __float2bfloat16(mv * naA[j]);
#pragma unroll
        for (int nt = 0; nt < 4; ++nt) {
            acc[nt] = __builtin_amdgcn_mfma_f32_16x16x32_bf16(au.v, bh[nt], acc[nt], 0, 0, 0);
            acc[nt] = __builtin_amdgcn_mfma_f32_16x16x32_bf16(au.v, bl[nt], acc[nt], 0, 0, 0);
        }
    }
#pragma unroll
    for (int nt = 0; nt < 4; ++nt)
#pragma unroll
        for (int r = 0; r < 4; ++r) part_s[w][q * 4 + r][nt * 16 + c16] = acc[nt][r];
}

// ---------------- K1: embed -> h fp32 + hb (q-sectioned) + agg zero ----------------
__global__ __launch_bounds__(256) void k_embed_hb(
        const float* __restrict__ x, const float* __restrict__ anf,
        const float* __restrict__ na, const float* __restrict__ W_emb,
        const float* __restrict__ b_emb,
        float* __restrict__ h, __hip_bfloat16* __restrict__ hb, float* __restrict__ agg) {
    __shared__ float xs[16][18];
    __shared__ float na_s[16][8];
    int tid = threadIdx.x, w = tid >> 6, l = tid & 63;
    int n0 = blockIdx.x * 16;
    {
        int r = tid >> 4, c = tid & 15;
        xs[r][c] = x[(size_t)(n0 + r) * 16 + c];
    }
    if (tid < 16) xs[tid][16] = anf[n0 + tid];
    if (tid < 128) na_s[tid >> 3][tid & 7] = na[(size_t)n0 * 8 + tid];
    float4 z4 = {0.f, 0.f, 0.f, 0.f};
    ((float4*)(agg + (size_t)blockIdx.x * 1024))[tid] = z4;
    // zero hb rows (16 x 96 bf16 = 192 float4)
    for (int t = tid; t < 192; t += 256)
        ((float4*)(hb + (size_t)n0 * HS))[t] = z4;
    __syncthreads();
    float acc[4];
#pragma unroll
    for (int t = 0; t < 4; ++t) acc[t] = b_emb[l];
    for (int i = 0; i < 17; ++i) {
#pragma unroll
        for (int j = 0; j < 8; ++j) {
            float wv = W_emb[(i * 8 + j) * 64 + l];
#pragma unroll
            for (int t = 0; t < 4; ++t) {
                int nn = w * 4 + t;
                acc[t] = fmaf(xs[nn][i] * na_s[nn][j], wv, acc[t]);
            }
        }
    }
    int slot = (l / 17) * 24 + l % 17;
#pragma unroll
    for (int t = 0; t < 4; ++t) {
        int n = n0 + w * 4 + t;
        h[(size_t)n * 64 + l] = acc[t];
        hb[(size_t)n * HS + slot] = __float2bfloat16(acc[t]);
    }
    if (tid < 16) hb[(size_t)(n0 + tid) * HS + 85] = __float2bfloat16(xs[tid][16]);  // i=64 -> 3*24+13
}

// ---------------- K3: edge kernel — register-fed z-GEMMs, per-lane global hb gather ----------------
__global__ __launch_bounds__(256, 3) void k_edge(
        const int* __restrict__ eidx, const float* __restrict__ ea,
        const float* __restrict__ amf, const __hip_bfloat16* __restrict__ hb,
        const __hip_bfloat16* __restrict__ W1hi, const float* __restrict__ bm1_l,
        const __hip_bfloat16* __restrict__ W2hi, const __hip_bfloat16* __restrict__ W2lo,
        const float* __restrict__ bm2_l, float* __restrict__ agg) {
    __shared__ __align__(16) __hip_bfloat16 m_s[128 * MS];
    __shared__ float ea_s[128][9];
    __shared__ float amf_s[128];
    __shared__ int src_s[128], dst_s[128];
    __shared__ float bm1_s[64], bm2_s[64];
    int tid = threadIdx.x;
    int l = tid & 63, w = tid >> 6;
    int e0 = blockIdx.x * 128;
    for (int idx = tid; idx < 128; idx += 256) {
        src_s[idx] = eidx[e0 + idx];
        dst_s[idx] = eidx[E + e0 + idx];
        amf_s[idx] = amf[e0 + idx];
    }
    for (int idx = tid; idx < 1024; idx += 256) ea_s[idx >> 3][idx & 7] = ea[(size_t)e0 * 8 + idx];
    if (tid < 64) { bm1_s[tid] = bm1_l[tid]; bm2_s[tid] = bm2_l[tid]; }
    __syncthreads();

    int c16 = l & 15, q = l >> 4;
    int e0w = w * 32;
    float eaA[2][8];
    float amfA[2];
#pragma unroll
    for (int mt = 0; mt < 2; ++mt) {
#pragma unroll
        for (int j = 0; j < 8; ++j) eaA[mt][j] = ea_s[e0w + mt * 16 + c16][j];
        amfA[mt] = amf_s[e0w + mt * 16 + c16];
    }
    int lofs = (c16 * 4 + q) * 8;
    f32x4 zero4 = {0.f, 0.f, 0.f, 0.f};

    // per-lane global gather of this lane's q-section of dst/src h_aug rows (L2-resident hb)
    bf16x4 xD[2][5], xS[2][5];
#pragma unroll
    for (int mt = 0; mt < 2; ++mt) {
        const __hip_bfloat16* bd = hb + (size_t)dst_s[e0w + mt * 16 + c16] * HS + q * 24;
        const __hip_bfloat16* bs = hb + (size_t)src_s[e0w + mt * 16 + c16] * HS + q * 24;
#pragma unroll
        for (int t = 0; t < 5; ++t) {
            xD[mt][t] = *(const bf16x4*)(bd + t * 4);
            xS[mt][t] = *(const bf16x4*)(bs + t * 4);
        }
    }

    // ---- phase 1: m1 z-GEMM, 35 chunks (17 dst + 17 src + 1 amf), register-fed A ----
    f32x4 acc1[2][4];
#pragma unroll
    for (int mt = 0; mt < 2; ++mt)
#pragma unroll
        for (int nt = 0; nt < 4; ++nt) acc1[mt][nt] = zero4;
#pragma unroll
    for (int kk = 0; kk < 17; ++kk) {
        bf16x8 bh[4];
#pragma unroll
        for (int nt = 0; nt < 4; ++nt)
            bh[nt] = *(const bf16x8*)(W1hi + (kk * 4 + nt) * 512 + lofs);
#pragma unroll
        for (int mt = 0; mt < 2; ++mt) {
            float xv = bf2f(xD[mt][kk >> 2][kk & 3]);
            union { bf16x8 v; __hip_bfloat16 hx[8]; } au;
#pragma unroll
            for (int j = 0; j < 8; ++j) au.hx[j] = __float2bfloat16(xv * eaA[mt][j]);
#pragma unroll
            for (int nt = 0; nt < 4; ++nt)
                acc1[mt][nt] = __builtin_amdgcn_mfma_f32_16x16x32_bf16(au.v, bh[nt], acc1[mt][nt], 0, 0, 0);
        }
    }
#pragma unroll
    for (int kk = 0; kk < 17; ++kk) {
        bf16x8 bh[4];
#pragma unroll
        for (int nt = 0; nt < 4; ++nt)
            bh[nt] = *(const bf16x8*)(W1hi + ((17 + kk) * 4 + nt) * 512 + lofs);
#pragma unroll
        for (int mt = 0; mt < 2; ++mt) {
            float xv = bf2f(xS[mt][kk >> 2][kk & 3]);
            union { bf16x8 v; __hip_bfloat16 hx[8]; } au;
#pragma unroll
            for (int j = 0; j < 8; ++j) au.hx[j] = __float2bfloat16(xv * eaA[mt][j]);
#pragma unroll
            for (int nt = 0; nt < 4; ++nt)
                acc1[mt][nt] = __builtin_amdgcn_mfma_f32_16x16x32_bf16(au.v, bh[nt], acc1[mt][nt], 0, 0, 0);
        }
    }
    {   // amf chunk (kk=34): only q==0 rows carry amf
        bf16x8 bh[4];
#pragma unroll
        for (int nt = 0; nt < 4; ++nt)
            bh[nt] = *(const bf16x8*)(W1hi + (34 * 4 + nt) * 512 + lofs);
#pragma unroll
        for (int mt = 0; mt < 2; ++mt) {
            float xv = (q == 0) ? amfA[mt] : 0.f;
            union { bf16x8 v; __hip_bfloat16 hx[8]; } au;
#pragma unroll
            for (int j = 0; j < 8; ++j) au.hx[j] = __float2bfloat16(xv * eaA[mt][j]);
#pragma unroll
            for (int nt = 0; nt < 4; ++nt)
                acc1[mt][nt] = __builtin_amdgcn_mfma_f32_16x16x32_bf16(au.v, bh[nt], acc1[mt][nt], 0, 0, 0);
        }
    }
    // extract m = silu(bm1 + m1) into m_s (wave-private rows; DS pipe per-wave in-order)
#pragma unroll
    for (int mt = 0; mt < 2; ++mt)
#pragma unroll
        for (int nt = 0; nt < 4; ++nt) {
            int kd = nt * 16 + c16;
            float bias = bm1_s[kd];
#pragma unroll
            for (int r = 0; r < 4; ++r) {
                int e = e0w + mt * 16 + q * 4 + r;
                m_s[e * MS + kd] = __float2bfloat16(silu_f(bias + acc1[mt][nt][r]));
            }
        }

    // ---- phase 2: m2 z-GEMM (q-major: lane reads contiguous m[q*16..q*16+15]) ----
    bf16x4 mR[2][4];
#pragma unroll
    for (int mt = 0; mt < 2; ++mt)
#pragma unroll
        for (int t = 0; t < 4; ++t)
            mR[mt][t] = *(const bf16x4*)&m_s[(e0w + mt * 16 + c16) * MS + q * 16 + t * 4];

    f32x4 acc[2][4];
#pragma unroll
    for (int mt = 0; mt < 2; ++mt)
#pragma unroll
        for (int nt = 0; nt < 4; ++nt) acc[mt][nt] = zero4;
#pragma unroll
    for (int kk = 0; kk < 16; ++kk) {
        bf16x8 bh[4], bl[4];
#pragma unroll
        for (int nt = 0; nt < 4; ++nt) {
            int off = (kk * 4 + nt) * 512 + lofs;
            bh[nt] = *(const bf16x8*)(W2hi + off);
            bl[nt] = *(const bf16x8*)(W2lo + off);
        }
#pragma unroll
        for (int mt = 0; mt < 2; ++mt) {
            float mv = bf2f(mR[mt][kk >> 2][kk & 3]);
            union { bf16x8 v; __hip_bfloat16 h[8]; } au;
#pragma unroll
            for (int j = 0; j < 8; ++j) au.h[j] = __float2bfloat16(mv * eaA[mt][j]);
#pragma unroll
            for (int nt = 0; nt < 4; ++nt) {
                acc[mt][nt] = __builtin_amdgcn_mfma_f32_16x16x32_bf16(au.v, bh[nt], acc[mt][nt], 0, 0, 0);
                acc[mt][nt] = __builtin_amdgcn_mfma_f32_16x16x32_bf16(au.v, bl[nt], acc[mt][nt], 0, 0, 0);
            }
        }
    }
#pragma unroll
    for (int mt = 0; mt < 2; ++mt)
#pragma unroll
        for (int nt = 0; nt < 4; ++nt) {
            int kd = nt * 16 + c16;
            float bias = bm2_s[kd];
#pragma unroll
            for (int r = 0; r < 4; ++r) {
                int e = e0w + mt * 16 + q * 4 + r;
                float v = silu_f(bias + acc[mt][nt][r]);
                atomicAdd(&agg[(size_t)dst_s[e] * 64 + kd], v);
            }
        }
}

// ---------------- K4: node update + write h/hb + agg zero ----------------
__global__ __launch_bounds__(256) void k_upd_hb(
        const float* __restrict__ h_in, const float* __restrict__ anf,
        const float* __restrict__ na, const float* __restrict__ agg_in,
        const __hip_bfloat16* __restrict__ W1hi, const __hip_bfloat16* __restrict__ W1lo,
        const float* __restrict__ bu1_l,
        const __hip_bfloat16* __restrict__ W2hi_, const __hip_bfloat16* __restrict__ W2lo_,
        const float* __restrict__ bu2_l,
        float* __restrict__ h, __hip_bfloat16* __restrict__ hb, float* __restrict__ agg) {
    __shared__ __align__(16) __hip_bfloat16 xa_s[16 * 136];
    __shared__ __align__(16) __hip_bfloat16 u1_s[16 * 72];
    __shared__ float part_s[4][16][64];
    int tid = threadIdx.x;
    int w = tid >> 6, l = tid & 63;
    int n0 = blockIdx.x * 16;
    for (int idx = tid; idx < 16 * 132; idx += 256) {
        int r = idx / 132, c = idx % 132;
        int n = n0 + r;
        float v;
        if (c < 64) v = h_in[(size_t)n * 64 + c];
        else if (c == 64) v = anf[n];
        else if (c < 129) v = agg_in[(size_t)n * 64 + (c - 65)];
        else v = 0.f;
        xa_s[r * 136 + c] = __float2bfloat16(v);
    }
    int c16 = l & 15, q = l >> 4;
    float naA[8];
#pragma unroll
    for (int j = 0; j < 8; ++j) naA[j] = na[(size_t)(n0 + c16) * 8 + j];
    __syncthreads();
    float4 z4 = {0.f, 0.f, 0.f, 0.f};
    ((float4*)(agg + (size_t)blockIdx.x * 1024))[tid] = z4;
    for (int t = tid; t < 192; t += 256)
        ((float4*)(hb + (size_t)n0 * HS))[t] = z4;
    int lofs = (c16 * 4 + q) * 8;
    zgemm_stage(xa_s, 136, 33, 33, w, c16, q, lofs, naA, W1hi, W1lo, part_s);
    __syncthreads();
    for (int t = tid; t < 1024; t += 256) {
        int row = t >> 6, col = t & 63;
        float v = part_s[0][row][col] + part_s[1][row][col] + part_s[2][row][col] +
                  part_s[3][row][col] + bu1_l[col];
        u1_s[row * 72 + col] = __float2bfloat16(silu_f(v));
    }
    __syncthreads();
    zgemm_stage(u1_s, 72, 16, 16, w, c16, q, lofs, naA, W2hi_, W2lo_, part_s);
    __syncthreads();
    for (int t = tid; t < 1024; t += 256) {
        int row = t >> 6, col = t & 63;
        float v = part_s[0][row][col] + part_s[1][row][col] + part_s[2][row][col] +
                  part_s[3][row][col] + bu2_l[col];
        int n = n0 + row;
        float hn = h[(size_t)n * 64 + col] + v;
        h[(size_t)n * 64 + col] = hn;
        hb[(size_t)n * HS + (col / 17) * 24 + col % 17] = __float2bfloat16(hn);
    }
    if (tid < 16) hb[(size_t)(n0 + tid) * HS + 85] = __float2bfloat16(anf[n0 + tid]);
}

// ---------------- K6: fused node update (layer 1) + prepool -> p2 ----------------
__global__ __launch_bounds__(256) void k_upd_prepool(
        const float* __restrict__ h_in, const float* __restrict__ anf,
        const float* __restrict__ na, const float* __restrict__ agg_in,
        const __hip_bfloat16* __restrict__ W1hi, const __hip_bfloat16* __restrict__ W1lo,
        const float* __restrict__ bu1_l,
        const __hip_bfloat16* __restrict__ W2hi_, const __hip_bfloat16* __restrict__ W2lo_,
        const float* __restrict__ bu2_l,
        const __hip_bfloat16* __restrict__ Wp1hi, const __hip_bfloat16* __restrict__ Wp1lo,
        const float* __restrict__ bp1,
        const __hip_bfloat16* __restrict__ Wp2hi, const __hip_bfloat16* __restrict__ Wp2lo,
        const float* __restrict__ bp2,
        float* __restrict__ p2) {
    __shared__ __align__(16) __hip_bfloat16 xa_s[16 * 136];
    __shared__ __align__(16) __hip_bfloat16 u1_s[16 * 72];
    __shared__ __align__(16) __hip_bfloat16 x2_s[16 * 72];
    __shared__ float part_s[4][16][64];
    int tid = threadIdx.x;
    int w = tid >> 6, l = tid & 63;
    int n0 = blockIdx.x * 16;
    for (int idx = tid; idx < 16 * 132; idx += 256) {
        int r = idx / 132, c = idx % 132;
        int n = n0 + r;
        float v;
        if (c < 64) v = h_in[(size_t)n * 64 + c];
        else if (c == 64) v = anf[n];
        else if (c < 129) v = agg_in[(size_t)n * 64 + (c - 65)];
        else v = 0.f;
        xa_s[r * 136 + c] = __float2bfloat16(v);
    }
    int c16 = l & 15, q = l >> 4;
    float naA[8];
#pragma unroll
    for (int j = 0; j < 8; ++j) naA[j] = na[(size_t)(n0 + c16) * 8 + j];
    __syncthreads();
    int lofs = (c16 * 4 + q) * 8;
    zgemm_stage(xa_s, 136, 33, 33, w, c16, q, lofs, naA, W1hi, W1lo, part_s);
    __syncthreads();
    for (int t = tid; t < 1024; t += 256) {
        int row = t >> 6, col = t & 63;
        float v = part_s[0][row][col] + part_s[1][row][col] + part_s[2][row][col] +
                  part_s[3][row][col] + bu1_l[col];
        u1_s[row * 72 + col] = __float2bfloat16(silu_f(v));
    }
    __syncthreads();
    zgemm_stage(u1_s, 72, 16, 16, w, c16, q, lofs, naA, W2hi_, W2lo_, part_s);
    __syncthreads();
    for (int t = tid; t < 1024; t += 256) {
        int row = t >> 6, col = t & 63;
        float v = part_s[0][row][col] + part_s[1][row][col] + part_s[2][row][col] +
                  part_s[3][row][col] + bu2_l[col];
        float hn = h_in[(size_t)(n0 + row) * 64 + col] + v;
        x2_s[row * 72 + col] = __float2bfloat16(hn);
    }
    __syncthreads();
    zgemm_stage(x2_s, 72, 16, 16, w, c16, q, lofs, naA, Wp1hi, Wp1lo, part_s);
    __syncthreads();
    for (int t = tid; t < 1024; t += 256) {
        int row = t >> 6, col = t & 63;
        float v = part_s[0][row][col] + part_s[1][row][col] + part_s[2][row][col] +
                  part_s[3][row][col] + bp1[col];
        u1_s[row * 72 + col] = __float2bfloat16(silu_f(v));
    }
    __syncthreads();
    zgemm_stage(u1_s, 72, 16, 16, w, c16, q, lofs, naA, Wp2hi, Wp2lo, part_s);
    __syncthreads();
    for (int t = tid; t < 1024; t += 256) {
        int row = t >> 6, col = t & 63;
        float v = part_s[0][row][col] + part_s[1][row][col] + part_s[2][row][col] +
                  part_s[3][row][col] + bp2[col];
        p2[(size_t)(n0 + row) * 64 + col] = v;
    }
}

// ---------------- K_pool ----------------
__global__ __launch_bounds__(256) void k_pool(
        const float* __restrict__ p2, const int* __restrict__ batch,
        float* __restrict__ partial_p, float* __restrict__ partial_cnt) {
    __shared__ float acc_s[16 * 64];
    __shared__ float cnt_s[16];
    int tid = threadIdx.x;
    for (int idx = tid; idx < 1024; idx += 256) acc_s[idx] = 0.f;
    if (tid < 16) cnt_s[tid] = 0.f;
    __syncthreads();
    int w = tid >> 6, k = tid & 63;
    int base = blockIdx.x * 125;
    for (int i = 0; i < 32; ++i) {
        int nl = i * 4 + w;
        if (nl < 125) {
            int n = base + nl;
            int b = batch[n];
            atomicAdd(&acc_s[b * 64 + k], p2[(size_t)n * 64 + k]);
            if (k == 0) atomicAdd(&cnt_s[b], 1.0f);
        }
    }
    __syncthreads();
    for (int idx = tid; idx < 1024; idx += 256)
        partial_p[(size_t)blockIdx.x * 1024 + idx] = acc_s[idx];
    if (tid < 16) partial_cnt[blockIdx.x * 16 + tid] = cnt_s[tid];
}

// ---------------- K7: reduce partials, mean, final MLP ----------------
__global__ __launch_bounds__(1024) void k_final(
        const float* __restrict__ partial_p, const float* __restrict__ partial_cnt,
        const float* __restrict__ Wq1, const float* __restrict__ bq1,
        const float* __restrict__ Wq2, const float* __restrict__ bq2,
        float* __restrict__ out) {
    __shared__ float g[16][64];
    int b = threadIdx.x >> 6, k = threadIdx.x & 63;
    float s = 0.f, cc = 0.f;
    for (int c = 0; c < POOL_CHUNKS; ++c) s += partial_p[(size_t)c * 1024 + b * 64 + k];
    for (int c = 0; c < POOL_CHUNKS; ++c) cc += partial_cnt[c * 16 + b];
    g[b][k] = s / fmaxf(cc, 1.0f);
    __syncthreads();
    float acc = bq1[k];
#pragma unroll
    for (int i = 0; i < 64; ++i) acc = fmaf(g[b][i], Wq1[i * 64 + k], acc);
    float v = silu_f(acc) * Wq2[k];
#pragma unroll
    for (int off = 32; off > 0; off >>= 1) v += __shfl_down(v, off, 64);
    if (k == 0) out[b] = v + bq2[0];
}

extern "C" void kernel_launch(void* const* d_in, const int* in_sizes, int n_in,
                              void* d_out, int out_size, void* d_ws, size_t ws_size,
                              hipStream_t stream) {
    const float* x    = (const float*)d_in[0];
    const int*   eidx = (const int*)  d_in[1];
    const float* ea   = (const float*)d_in[2];
    const float* na   = (const float*)d_in[3];
    const float* amf  = (const float*)d_in[4];
    const float* anf  = (const float*)d_in[5];
    const int*   batch= (const int*)  d_in[6];
    const float* W_emb= (const float*)d_in[7];
    const float* b_emb= (const float*)d_in[8];
    const float* Wm1  = (const float*)d_in[9];
    const float* bm1  = (const float*)d_in[10];
    const float* Wm2  = (const float*)d_in[11];
    const float* bm2  = (const float*)d_in[12];
    const float* Wu1  = (const float*)d_in[13];
    const float* bu1  = (const float*)d_in[14];
    const float* Wu2  = (const float*)d_in[15];
    const float* bu2  = (const float*)d_in[16];
    const float* Wp1  = (const float*)d_in[17];
    const float* bp1  = (const float*)d_in[18];
    const float* Wp2  = (const float*)d_in[19];
    const float* bp2  = (const float*)d_in[20];
    const float* Wq1  = (const float*)d_in[21];
    const float* bq1  = (const float*)d_in[22];
    const float* Wq2  = (const float*)d_in[23];
    const float* bq2  = (const float*)d_in[24];

    float* ws = (float*)d_ws;
    float* h      = ws;                            // N*64
    float* agg    = h + (size_t)N * 64;            // N*64
    float* p2     = agg + (size_t)N * 64;          // N*64
    float* part_p = p2 + (size_t)N * 64;           // 80*1024
    float* part_c = part_p + POOL_CHUNKS * 1024;   // 80*16
    float* fend   = part_c + POOL_CHUNKS * 16;
    __hip_bfloat16* hb     = (__hip_bfloat16*)fend;          // N*96
    __hip_bfloat16* W2hi   = hb + (size_t)N * HS;
    __hip_bfloat16* W2lo   = W2hi + 65536;
    __hip_bfloat16* Wu2hi  = W2lo + 65536;
    __hip_bfloat16* Wu2lo  = Wu2hi + 65536;
    __hip_bfloat16* Wp1hi  = Wu2lo + 65536;
    __hip_bfloat16* Wp1lo  = Wp1hi + 32768;
    __hip_bfloat16* Wp2hi  = Wp1lo + 32768;
    __hip_bfloat16* Wp2lo  = Wp2hi + 32768;
    __hip_bfloat16* Wu1hi  = Wp2lo + 32768;
    __hip_bfloat16* Wu1lo  = Wu1hi + 135168;
    __hip_bfloat16* Wm1zhi = Wu1lo + 135168;       // 2*71680

    k_w2<<<256, 256, 0, stream>>>(Wm2, W2hi, W2lo);
    k_w2<<<256, 256, 0, stream>>>(Wu2, Wu2hi, Wu2lo);
    k_w2<<<128, 256, 0, stream>>>(Wp1, Wp1hi, Wp1lo);
    k_w2<<<128, 256, 0, stream>>>(Wp2, Wp2hi, Wp2lo);
    k_wu1<<<528, 256, 0, stream>>>(Wu1, Wu1hi, Wu1lo);
    k_wm1z<<<560, 256, 0, stream>>>(Wm1, Wm1zhi);

    k_embed_hb<<<625, 256, 0, stream>>>(x, anf, na, W_emb, b_emb, h, hb, agg);
    k_edge<<<E / 128, 256, 0, stream>>>(eidx, ea, amf, hb,
                                        Wm1zhi, bm1,
                                        W2hi, W2lo, bm2, agg);
    k_upd_hb<<<625, 256, 0, stream>>>(h, anf, na, agg,
                                      Wu1hi, Wu1lo, bu1,
                                      Wu2hi, Wu2lo, bu2,
                                      h, hb, agg);
    k_edge<<<E / 128, 256, 0, stream>>>(eidx, ea, amf, hb,
                                        Wm1zhi + 71680, bm1 + 64,
                                        W2hi + 32768, W2lo + 32768, bm2 + 64, agg);
    k_upd_prepool<<<625, 256, 0, stream>>>(h, anf, na, agg,
                                           Wu1hi + 67584, Wu1lo + 67584, bu1 + 64,
                                           Wu2hi + 32768, Wu2lo + 32768, bu2 + 64,
                                           Wp1hi, Wp1lo, bp1, Wp2hi, Wp2lo, bp2, p2);
    k_pool<<<POOL_CHUNKS, 256, 0, stream>>>(p2, batch, part_p, part_c);
    k_final<<<1, 1024, 0, stream>>>(part_p, part_c, Wq1, bq1, Wq2, bq2, (float*)d_out);
}